// Round 12
// baseline (808.444 us; speedup 1.0000x reference)
//
#include <hip/hip_runtime.h>
#include <stdint.h>

#define HIST 336
#define CNTX 168
#define PRED 24
#define HID 128
#define NFEAT 5
#define EMB 50
#define NLAGS 168
#define IN_DIM 218
#define NSAMP 8192
#define G3 384

// workspace layout (float offsets)
#define WS_XS     0
#define WS_SC     336
#define WS_TF     340
#define WS_YM     8740
#define WS_KEYS   9940
#define WS_ENCGI  10036
#define WS_WQ     10036
#define WS_GISH   74548
#define WS_HLAST  83764
#define WS_WIHT   83892

typedef float v2f __attribute__((ext_vector_type(2)));
// forced packed fp32 FMA: acc = a*b + acc (two independent IEEE fmas per lane)
__device__ __forceinline__ void pkfma(v2f &acc, v2f a, v2f b){
  asm("v_pk_fma_f32 %0, %1, %2, %0" : "+v"(acc) : "v"(a), "v"(b));
}

// ---------------- threefry2x32 core (20 rounds) ----------------
__device__ __forceinline__ uint32_t rotl32(uint32_t v, int r){ return (v<<r)|(v>>(32-r)); }

__device__ __forceinline__ void threefry(uint32_t k0, uint32_t k1, uint32_t x0, uint32_t x1,
                                         uint32_t &o0, uint32_t &o1){
  uint32_t ks2 = k0 ^ k1 ^ 0x1BD11BDAu;
  x0 += k0; x1 += k1;
#define TFR(a) { x0 += x1; x1 = rotl32(x1,(a)); x1 ^= x0; }
  TFR(13) TFR(15) TFR(26) TFR(6)
  x0 += k1; x1 += ks2 + 1u;
  TFR(17) TFR(29) TFR(16) TFR(24)
  x0 += ks2; x1 += k0 + 2u;
  TFR(13) TFR(15) TFR(26) TFR(6)
  x0 += k0; x1 += k1 + 3u;
  TFR(17) TFR(29) TFR(16) TFR(24)
  x0 += k1; x1 += ks2 + 4u;
  TFR(13) TFR(15) TFR(26) TFR(6)
  x0 += ks2; x1 += k0 + 5u;
#undef TFR
  o0 = x0; o1 = x1;
}

// ---------------- partitionable (foldlike) JAX PRNG semantics ----------------
__device__ __forceinline__ void tf_split2(uint32_t k0, uint32_t k1,
                                          uint32_t &a0, uint32_t &a1,
                                          uint32_t &b0, uint32_t &b1){
  threefry(k0,k1, 0u,0u, a0,a1);
  threefry(k0,k1, 0u,1u, b0,b1);
}

__device__ __forceinline__ void tf_split3(uint32_t k0, uint32_t k1,
                                          uint32_t &a0, uint32_t &a1,
                                          uint32_t &b0, uint32_t &b1,
                                          uint32_t &c0, uint32_t &c1){
  threefry(k0,k1, 0u,0u, a0,a1);
  threefry(k0,k1, 0u,1u, b0,b1);
  threefry(k0,k1, 0u,2u, c0,c1);
}

__device__ __forceinline__ uint32_t tf_bits1(uint32_t k0, uint32_t k1){
  uint32_t o0,o1; threefry(k0,k1, 0u,0u, o0,o1); return o0 ^ o1;
}

__device__ __forceinline__ uint32_t tf_bits_at(uint32_t k0, uint32_t k1, uint32_t i){
  uint32_t o0,o1; threefry(k0,k1, 0u,i, o0,o1); return o0 ^ o1;
}

__device__ __forceinline__ float bits_to_f01(uint32_t b){
  return __uint_as_float((b>>9) | 0x3f800000u) - 1.0f;
}

// XLA ErfInv32 polynomial
__device__ __forceinline__ float erfinv32(float x){
  float w = -log1pf(-x*x);
  float p;
  if (w < 5.0f){
    w = w - 2.5f;
    p = 2.81022636e-08f;
    p = fmaf(p, w, 3.43273939e-07f);
    p = fmaf(p, w, -3.5233877e-06f);
    p = fmaf(p, w, -4.39150654e-06f);
    p = fmaf(p, w, 0.00021858087f);
    p = fmaf(p, w, -0.00125372503f);
    p = fmaf(p, w, -0.00417768164f);
    p = fmaf(p, w, 0.246640727f);
    p = fmaf(p, w, 1.50140941f);
  } else {
    w = sqrtf(w) - 3.0f;
    p = -0.000200214257f;
    p = fmaf(p, w, 0.000100950558f);
    p = fmaf(p, w, 0.00134934322f);
    p = fmaf(p, w, -0.00367342844f);
    p = fmaf(p, w, 0.00573950773f);
    p = fmaf(p, w, -0.0076224613f);
    p = fmaf(p, w, 0.00943887047f);
    p = fmaf(p, w, 1.00167406f);
    p = fmaf(p, w, 2.83297682f);
  }
  return p*x;
}

__device__ __forceinline__ float normal_from_key(uint32_t k0, uint32_t k1){
  uint32_t b = tf_bits1(k0,k1);
  const float lo = -0.99999994f;
  float f = bits_to_f01(b);
  float u = fmaxf(lo, f*2.0f + lo);
  return 1.41421356f * erfinv32(u);
}

// JAX _gamma_one, alpha >= 1 branch (boost==1)
__device__ float gamma_sample(uint32_t k0, uint32_t k1, float alpha){
  float d = __fsub_rn(alpha, 0.33333334f);
  float c = 0.33333334f / sqrtf(d);
  uint32_t ck0,ck1, sb0,sb1;
  tf_split2(k0,k1, ck0,ck1, sb0,sb1);
  float V;
  for(;;){
    uint32_t nk0,nk1, xk0,xk1, uk0,uk1;
    tf_split3(ck0,ck1, nk0,nk1, xk0,xk1, uk0,uk1);
    ck0=nk0; ck1=nk1;
    float x, v;
    do {
      uint32_t xa0,xa1, xb0,xb1;
      tf_split2(xk0,xk1, xa0,xa1, xb0,xb1);
      xk0=xa0; xk1=xa1;
      x = normal_from_key(xb0,xb1);
      v = __fadd_rn(1.0f, __fmul_rn(x, c));
    } while (v <= 0.0f);
    float X  = __fmul_rn(x, x);
    float Vv = __fmul_rn(__fmul_rn(v, v), v);
    float U  = bits_to_f01(tf_bits1(uk0,uk1));
    float t1 = __fsub_rn(1.0f, __fmul_rn(0.0331f, __fmul_rn(X, X)));
    bool cont = (U >= t1);
    if (cont){
      float lhs = logf(U);
      float rhs = __fadd_rn(__fmul_rn(0.5f, X),
                  __fmul_rn(d, __fadd_rn(__fsub_rn(1.0f, Vv), logf(Vv))));
      cont = (lhs >= rhs);
    }
    if (!cont){ V = Vv; break; }
  }
  return d*V;
}

__device__ __forceinline__ float softplus_f(float x){
  float amax = fmaxf(x, 0.0f);
  return amax + log1pf(expf(-fabsf(x)));
}

// ---------------- K1: scale, xs, tf, ym, step keys ----------------
__global__ __launch_bounds__(256) void k1_prep(const float* __restrict__ x,
                                               const float* __restrict__ xmark,
                                               const float* __restrict__ ymark,
                                               const float* __restrict__ Wemb,
                                               const float* __restrict__ bemb,
                                               float* __restrict__ ws){
  __shared__ float red[256];
  __shared__ float s_sc;
  int t = threadIdx.x;
  float a = 0.f;
  if (t < CNTX) a = fabsf(x[CNTX + t]);
  red[t] = a;
  __syncthreads();
  for(int s=128; s>0; s>>=1){ if(t<s) red[t]+=red[t+s]; __syncthreads(); }
  if (t==0){ s_sc = fmaxf(red[0]/168.0f, 1e-5f); ws[WS_SC]=s_sc; }
  __syncthreads();
  float sc = s_sc;
  for(int i=t; i<HIST; i+=256) ws[WS_XS+i] = x[i]/sc;
  for(int idx=t; idx<CNTX*EMB; idx+=256){
    int tt = idx/EMB, e = idx%EMB;
    float acc = bemb[e];
    for(int f=0; f<NFEAT; f++) acc += xmark[(CNTX+tt)*NFEAT+f]*Wemb[f*EMB+e];
    ws[WS_TF+idx] = acc;
  }
  for(int idx=t; idx<PRED*EMB; idx+=256){
    int kk = idx/EMB, e = idx%EMB;
    float acc = bemb[e];
    for(int f=0; f<NFEAT; f++) acc += ymark[kk*NFEAT+f]*Wemb[f*EMB+e];
    ws[WS_YM+idx] = acc;
  }
  if (t==0){
    uint32_t* kp = reinterpret_cast<uint32_t*>(ws + WS_KEYS);
    uint32_t c0 = 0u, c1 = 42u;
    for(int k=0;k<PRED;k++){
      uint32_t a0,a1,b0,b1;
      tf_split2(c0,c1, a0,a1, b0,b1);
      c0=a0; c1=a1;
      uint32_t n0,n1,g0,g1;
      tf_split2(b0,b1, n0,n1, g0,g1);
      kp[k*4+0]=n0; kp[k*4+1]=n1; kp[k*4+2]=g0; kp[k*4+3]=g1;
    }
  }
}

// ---------------- K2: enc_gi (t<168) and gi_shared (t>=168) ----------------
__global__ __launch_bounds__(256) void k2_gi(const float* __restrict__ Wih,
                                             const float* __restrict__ bih,
                                             const float* __restrict__ bhh,
                                             float* __restrict__ ws){
  int idx = blockIdx.x*256 + threadIdx.x;
  if (idx >= 192*G3) return;
  int t = idx / G3, r = idx % G3;
  const float* wr = Wih + r*IN_DIM;
  const float* xs = ws + WS_XS;
  float acc = bih[r] + (r < 256 ? bhh[r] : 0.0f);
  if (t < CNTX){
    const float* tf = ws + WS_TF + t*EMB;
    for(int j=0;j<NLAGS;j++) acc += wr[j]*xs[CNTX + t - 1 - j];
    for(int e=0;e<EMB;e++)   acc += wr[NLAGS+e]*tf[e];
    ws[WS_ENCGI + t*G3 + r] = acc;
  } else {
    int k = t - CNTX;
    const float* ym = ws + WS_YM + k*EMB;
    for(int e=0;e<EMB;e++)   acc += wr[NLAGS+e]*ym[e];
    for(int i=k;i<NLAGS;i++) acc += wr[i]*xs[HIST-1-i+k];
    ws[WS_GISH + k*G3 + r] = acc;
  }
}

// ---------------- K2b: wihT transpose (idx < 24*G3) + Wq build (after k3 uses encgi? no —
//   Wq overwrites ENCGI, must run AFTER k3. Keep separate k5 ordering: this kernel only wihT. ----
__global__ __launch_bounds__(256) void k2b_wiht(const float* __restrict__ Wih,
                                                float* __restrict__ ws){
  int idx = blockIdx.x*256 + threadIdx.x;
  if (idx >= PRED*G3) return;
  int r = idx / PRED, i = idx % PRED;
  ws[WS_WIHT + i*G3 + r] = Wih[r*IN_DIM + i];
}

// ---------------- K3: encoder GRU (unchanged from passing r5/r6) ----------------
__global__ __launch_bounds__(384) void k3_enc(const float* __restrict__ Whh,
                                              const float* __restrict__ bhh,
                                              float* __restrict__ ws){
  __shared__ __align__(16) float h[HID];
  __shared__ float grz[256];
  __shared__ float hnv[HID];
  int r = threadIdx.x;
  float4 w[32];
  const float4* wr = (const float4*)(Whh + r*HID);
  #pragma unroll
  for(int i=0;i<32;i++) w[i] = wr[i];
  float bh = (r>=256)? bhh[r] : 0.0f;
  if (r < HID) h[r] = 0.0f;
  __syncthreads();
  const float* encgi = ws + WS_ENCGI;
  for(int t=0;t<CNTX;t++){
    float acc = 0.f;
    #pragma unroll
    for(int i=0;i<32;i++){
      float4 hv = *(const float4*)&h[4*i];
      float4 ww = w[i];
      acc = fmaf(ww.x,hv.x, fmaf(ww.y,hv.y, fmaf(ww.z,hv.z, fmaf(ww.w,hv.w, acc))));
    }
    if (r < 256) grz[r] = encgi[t*G3+r] + acc;
    else         hnv[r-256] = acc + bh;
    __syncthreads();
    if (r < HID){
      float rr = 1.0f/(1.0f+expf(-grz[r]));
      float zz = 1.0f/(1.0f+expf(-grz[128+r]));
      float inv = encgi[t*G3+256+r];
      float nn = tanhf(inv + rr*hnv[r]);
      h[r] = (1.0f-zz)*nn + zz*h[r];
    }
    __syncthreads();
  }
  if (r < HID) ws[WS_HLAST + r] = h[r];
}

// ---------------- K5: build Wq[q][r] = float4 W[r][4q..4q+3] (into dead ENCGI area) ----------------
__global__ __launch_bounds__(256) void k5_wq(const float* __restrict__ Whh,
                                             float* __restrict__ ws){
  int idx = blockIdx.x*256 + threadIdx.x;
  if (idx >= 32*G3) return;
  int q = idx / G3, r = idx % G3;
  float4 v = *(const float4*)&Whh[r*HID + q*4];
  ((float4*)(ws + WS_WQ))[idx] = v;
}

// ---------------- K4: decoder — SPB=32, W streamed w/ prefetch, forced v_pk_fma_f32 ------
// 256 blocks x 512 threads. Thread (rg=t&127, sg=t>>7) owns rows {rg,128+rg,256+rg} and
// samples s0=8*sg..+7. Gates fused in-thread. Accumulation chains identical to r5..r10:
// init gish/bhh -> lags i-ascending -> W.h dims 4q+c ascending.
#define SPB 32
#define THR4 512

__global__ __launch_bounds__(512) void k4_dec(const float* __restrict__ Whh,
                                              const float* __restrict__ bhh,
                                              const float* __restrict__ Wproj,
                                              const float* __restrict__ bproj,
                                              const float* __restrict__ ws,
                                              float* __restrict__ out){
  __shared__ __align__(16) float4 hT4[128][9];   // 18.4 KB
  __shared__ float wihT_l[24*G3];                // 36.9 KB
  __shared__ float shistT[25][34];               // 3.4 KB
  __shared__ float parr[SPB][4];
  __shared__ float wp[HID*3];
  __shared__ float bp[3];
  __shared__ uint32_t skeys[PRED*4];

  int t = threadIdx.x;
  int b = blockIdx.x;
  int rg = t & 127;
  int sg = t >> 7;      // 0..3
  int s0 = sg*8;
  int g0 = sg*2;

  float bhn = bhh[256 + rg];

  for(int idx=t; idx<24*G3; idx+=THR4) wihT_l[idx] = ws[WS_WIHT + idx];
  for(int idx=t; idx<HID*3; idx+=THR4) wp[idx] = Wproj[idx];
  if (t < 3) bp[t] = bproj[t];
  if (t < PRED*4) skeys[t] = reinterpret_cast<const uint32_t*>(ws + WS_KEYS)[t];
  if (t < 128){
    float hl = ws[WS_HLAST + t];
    float4 v = {hl,hl,hl,hl};
    #pragma unroll
    for(int g=0;g<8;g++) hT4[t][g] = v;
  }
  float hold[8];
  {
    float hl = ws[WS_HLAST + rg];
    #pragma unroll
    for(int s=0;s<8;s++) hold[s] = hl;
  }
  float sc = ws[WS_SC];
  const float* gish = ws + WS_GISH;
  const float4* Wq4 = (const float4*)(ws + WS_WQ);
  __syncthreads();

  #pragma unroll 1
  for(int k=0;k<PRED;k++){
    v2f aR[4], aZ[4], aH[4], aI[4];
    {
      float gR = gish[k*G3 + rg];
      float gZ = gish[k*G3 + 128 + rg];
      float gI = gish[k*G3 + 256 + rg];
      #pragma unroll
      for(int p=0;p<4;p++){
        aR[p] = (v2f){gR,gR}; aZ[p] = (v2f){gZ,gZ};
        aI[p] = (v2f){gI,gI}; aH[p] = (v2f){bhn,bhn};
      }
    }
    // lag chains (i ascending — identical order)
    #pragma unroll 1
    for(int i=0;i<k;i++){
      float wR = wihT_l[i*G3 + rg];
      float wZ = wihT_l[i*G3 + 128 + rg];
      float wN = wihT_l[i*G3 + 256 + rg];
      v2f wR2 = {wR,wR}, wZ2 = {wZ,wZ}, wN2 = {wN,wN};
      #pragma unroll
      for(int p=0;p<4;p++){
        v2f sh = *(const v2f*)&shistT[k-1-i][s0 + 2*p];
        pkfma(aR[p], wR2, sh);
        pkfma(aZ[p], wZ2, sh);
        pkfma(aI[p], wN2, sh);
      }
    }
    // main W.h with distance-1 prefetch: dims 4q+c ascending (identical chain)
    {
      float4 wr4 = Wq4[0*G3 + rg];
      float4 wz4 = Wq4[0*G3 + 128 + rg];
      float4 wn4 = Wq4[0*G3 + 256 + rg];
      #pragma unroll 1
      for(int q=0;q<32;q++){
        float4 nr, nz, nn_;
        if (q < 31){
          nr  = Wq4[(q+1)*G3 + rg];
          nz  = Wq4[(q+1)*G3 + 128 + rg];
          nn_ = Wq4[(q+1)*G3 + 256 + rg];
        }
        #pragma unroll
        for(int c=0;c<4;c++){
          float wrc = (c==0)?wr4.x:(c==1)?wr4.y:(c==2)?wr4.z:wr4.w;
          float wzc = (c==0)?wz4.x:(c==1)?wz4.y:(c==2)?wz4.z:wz4.w;
          float wnc = (c==0)?wn4.x:(c==1)?wn4.y:(c==2)?wn4.z:wn4.w;
          v2f wr2 = {wrc,wrc}, wz2 = {wzc,wzc}, wn2 = {wnc,wnc};
          #pragma unroll
          for(int g=0;g<2;g++){
            float4 hv = hT4[4*q + c][g0 + g];
            v2f lo = {hv.x, hv.y}, hi = {hv.z, hv.w};
            pkfma(aR[2*g],   wr2, lo);
            pkfma(aR[2*g+1], wr2, hi);
            pkfma(aZ[2*g],   wz2, lo);
            pkfma(aZ[2*g+1], wz2, hi);
            pkfma(aH[2*g],   wn2, lo);
            pkfma(aH[2*g+1], wn2, hi);
          }
        }
        wr4 = nr; wz4 = nz; wn4 = nn_;
      }
    }
    __syncthreads();   // all hT4 (old h) reads complete
    // gates fused in-thread (identical per-cell formulas)
    #pragma unroll
    for(int s=0;s<8;s++){
      int p = s >> 1, e = s & 1;
      float aRv = aR[p][e], aZv = aZ[p][e], aIv = aI[p][e], aHv = aH[p][e];
      float rr = 1.0f/(1.0f+expf(-aRv));
      float zz = 1.0f/(1.0f+expf(-aZv));
      float nn = tanhf(aIv + rr*aHv);
      float hn = (1.0f-zz)*nn + zz*hold[s];
      hold[s] = hn;
      ((float*)&hT4[rg][g0 + (s>>2)])[s & 3] = hn;
    }
    __syncthreads();
    // projection: 96 threads (identical l-order); h[s][l] at word l*36+s
    if (t < SPB*3){
      int s = t/3, c2 = t%3;
      const float* hT = (const float*)hT4;
      float acc = bp[c2];
      for(int l=0;l<HID;l++) acc = fmaf(hT[l*36 + s], wp[l*3+c2], acc);
      parr[s][c2] = acc;
    }
    __syncthreads();
    // sampling: 32 threads (identical math/order)
    if (t < SPB){
      int s = t, gs = b*SPB + s;
      float p0 = parr[s][0], loc = parr[s][1], p2 = parr[s][2];
      float df = 2.0f + softplus_f(p0);
      float half_df = df*0.5f;
      float sigma = softplus_f(p2);
      uint32_t kn0 = skeys[k*4+0], kn1 = skeys[k*4+1];
      uint32_t kg0 = skeys[k*4+2], kg1 = skeys[k*4+3];
      uint32_t bnb = tf_bits_at(kn0, kn1, (uint32_t)gs);
      const float lo = -0.99999994f;
      float un = fmaxf(lo, bits_to_f01(bnb)*2.0f + lo);
      float nval = 1.41421356f * erfinv32(un);
      uint32_t gk0, gk1;
      threefry(kg0, kg1, 0u, (uint32_t)gs, gk0, gk1);
      float gmm = gamma_sample(gk0, gk1, half_df);
      float tval = nval * sqrtf(half_df / gmm);
      float samp = (loc + sigma*tval)*sc;
      out[gs*PRED + k] = samp;
      shistT[k][s] = samp / sc;
    }
    __syncthreads();
  }
}

extern "C" void kernel_launch(void* const* d_in, const int* in_sizes, int n_in,
                              void* d_out, int out_size, void* d_ws, size_t ws_size,
                              hipStream_t stream){
  const float* x     = (const float*)d_in[0];
  const float* xmark = (const float*)d_in[1];
  const float* ymark = (const float*)d_in[2];
  const float* Wemb  = (const float*)d_in[3];
  const float* bemb  = (const float*)d_in[4];
  const float* Wih   = (const float*)d_in[5];
  const float* Whh   = (const float*)d_in[6];
  const float* bih   = (const float*)d_in[7];
  const float* bhh   = (const float*)d_in[8];
  const float* Wproj = (const float*)d_in[9];
  const float* bproj = (const float*)d_in[10];
  float* ws  = (float*)d_ws;
  float* out = (float*)d_out;

  hipLaunchKernelGGL(k1_prep, dim3(1), dim3(256), 0, stream, x, xmark, ymark, Wemb, bemb, ws);
  hipLaunchKernelGGL(k2_gi, dim3(288), dim3(256), 0, stream, Wih, bih, bhh, ws);
  hipLaunchKernelGGL(k2b_wiht, dim3((PRED*G3+255)/256), dim3(256), 0, stream, Wih, ws);
  hipLaunchKernelGGL(k3_enc, dim3(1), dim3(384), 0, stream, Whh, bhh, ws);
  hipLaunchKernelGGL(k5_wq, dim3((32*G3+255)/256), dim3(256), 0, stream, Whh, ws);
  hipLaunchKernelGGL(k4_dec, dim3(NSAMP/SPB), dim3(THR4), 0, stream, Whh, bhh, Wproj, bproj, ws, out);
}

// Round 13
// 786.173 us; speedup vs baseline: 1.0283x; 1.0283x over previous
//
#include <hip/hip_runtime.h>
#include <stdint.h>

#define HIST 336
#define CNTX 168
#define PRED 24
#define HID 128
#define NFEAT 5
#define EMB 50
#define NLAGS 168
#define IN_DIM 218
#define NSAMP 8192
#define G3 384

// workspace layout (float offsets)
#define WS_XS     0
#define WS_SC     336
#define WS_TF     340
#define WS_YM     8740
#define WS_KEYS   9940
#define WS_ENCGI  10036
#define WS_WQ     10036
#define WS_GISH   74548
#define WS_HLAST  83764
#define WS_WIHT   83892

typedef float v2f __attribute__((ext_vector_type(2)));
__device__ __forceinline__ v2f fma2(v2f a, v2f b, v2f c){ return __builtin_elementwise_fma(a,b,c); }

// ---------------- threefry2x32 core (20 rounds) ----------------
__device__ __forceinline__ uint32_t rotl32(uint32_t v, int r){ return (v<<r)|(v>>(32-r)); }

__device__ __forceinline__ void threefry(uint32_t k0, uint32_t k1, uint32_t x0, uint32_t x1,
                                         uint32_t &o0, uint32_t &o1){
  uint32_t ks2 = k0 ^ k1 ^ 0x1BD11BDAu;
  x0 += k0; x1 += k1;
#define TFR(a) { x0 += x1; x1 = rotl32(x1,(a)); x1 ^= x0; }
  TFR(13) TFR(15) TFR(26) TFR(6)
  x0 += k1; x1 += ks2 + 1u;
  TFR(17) TFR(29) TFR(16) TFR(24)
  x0 += ks2; x1 += k0 + 2u;
  TFR(13) TFR(15) TFR(26) TFR(6)
  x0 += k0; x1 += k1 + 3u;
  TFR(17) TFR(29) TFR(16) TFR(24)
  x0 += k1; x1 += ks2 + 4u;
  TFR(13) TFR(15) TFR(26) TFR(6)
  x0 += ks2; x1 += k0 + 5u;
#undef TFR
  o0 = x0; o1 = x1;
}

// ---------------- partitionable (foldlike) JAX PRNG semantics ----------------
__device__ __forceinline__ void tf_split2(uint32_t k0, uint32_t k1,
                                          uint32_t &a0, uint32_t &a1,
                                          uint32_t &b0, uint32_t &b1){
  threefry(k0,k1, 0u,0u, a0,a1);
  threefry(k0,k1, 0u,1u, b0,b1);
}

__device__ __forceinline__ void tf_split3(uint32_t k0, uint32_t k1,
                                          uint32_t &a0, uint32_t &a1,
                                          uint32_t &b0, uint32_t &b1,
                                          uint32_t &c0, uint32_t &c1){
  threefry(k0,k1, 0u,0u, a0,a1);
  threefry(k0,k1, 0u,1u, b0,b1);
  threefry(k0,k1, 0u,2u, c0,c1);
}

__device__ __forceinline__ uint32_t tf_bits1(uint32_t k0, uint32_t k1){
  uint32_t o0,o1; threefry(k0,k1, 0u,0u, o0,o1); return o0 ^ o1;
}

__device__ __forceinline__ uint32_t tf_bits_at(uint32_t k0, uint32_t k1, uint32_t i){
  uint32_t o0,o1; threefry(k0,k1, 0u,i, o0,o1); return o0 ^ o1;
}

__device__ __forceinline__ float bits_to_f01(uint32_t b){
  return __uint_as_float((b>>9) | 0x3f800000u) - 1.0f;
}

// XLA ErfInv32 polynomial
__device__ __forceinline__ float erfinv32(float x){
  float w = -log1pf(-x*x);
  float p;
  if (w < 5.0f){
    w = w - 2.5f;
    p = 2.81022636e-08f;
    p = fmaf(p, w, 3.43273939e-07f);
    p = fmaf(p, w, -3.5233877e-06f);
    p = fmaf(p, w, -4.39150654e-06f);
    p = fmaf(p, w, 0.00021858087f);
    p = fmaf(p, w, -0.00125372503f);
    p = fmaf(p, w, -0.00417768164f);
    p = fmaf(p, w, 0.246640727f);
    p = fmaf(p, w, 1.50140941f);
  } else {
    w = sqrtf(w) - 3.0f;
    p = -0.000200214257f;
    p = fmaf(p, w, 0.000100950558f);
    p = fmaf(p, w, 0.00134934322f);
    p = fmaf(p, w, -0.00367342844f);
    p = fmaf(p, w, 0.00573950773f);
    p = fmaf(p, w, -0.0076224613f);
    p = fmaf(p, w, 0.00943887047f);
    p = fmaf(p, w, 1.00167406f);
    p = fmaf(p, w, 2.83297682f);
  }
  return p*x;
}

__device__ __forceinline__ float normal_from_key(uint32_t k0, uint32_t k1){
  uint32_t b = tf_bits1(k0,k1);
  const float lo = -0.99999994f;
  float f = bits_to_f01(b);
  float u = fmaxf(lo, f*2.0f + lo);
  return 1.41421356f * erfinv32(u);
}

// JAX _gamma_one, alpha >= 1 branch (boost==1)
__device__ float gamma_sample(uint32_t k0, uint32_t k1, float alpha){
  float d = __fsub_rn(alpha, 0.33333334f);
  float c = 0.33333334f / sqrtf(d);
  uint32_t ck0,ck1, sb0,sb1;
  tf_split2(k0,k1, ck0,ck1, sb0,sb1);
  float V;
  for(;;){
    uint32_t nk0,nk1, xk0,xk1, uk0,uk1;
    tf_split3(ck0,ck1, nk0,nk1, xk0,xk1, uk0,uk1);
    ck0=nk0; ck1=nk1;
    float x, v;
    do {
      uint32_t xa0,xa1, xb0,xb1;
      tf_split2(xk0,xk1, xa0,xa1, xb0,xb1);
      xk0=xa0; xk1=xa1;
      x = normal_from_key(xb0,xb1);
      v = __fadd_rn(1.0f, __fmul_rn(x, c));
    } while (v <= 0.0f);
    float X  = __fmul_rn(x, x);
    float Vv = __fmul_rn(__fmul_rn(v, v), v);
    float U  = bits_to_f01(tf_bits1(uk0,uk1));
    float t1 = __fsub_rn(1.0f, __fmul_rn(0.0331f, __fmul_rn(X, X)));
    bool cont = (U >= t1);
    if (cont){
      float lhs = logf(U);
      float rhs = __fadd_rn(__fmul_rn(0.5f, X),
                  __fmul_rn(d, __fadd_rn(__fsub_rn(1.0f, Vv), logf(Vv))));
      cont = (lhs >= rhs);
    }
    if (!cont){ V = Vv; break; }
  }
  return d*V;
}

__device__ __forceinline__ float softplus_f(float x){
  float amax = fmaxf(x, 0.0f);
  return amax + log1pf(expf(-fabsf(x)));
}

// ---------------- K1: scale, xs, tf, ym, step keys ----------------
__global__ __launch_bounds__(256) void k1_prep(const float* __restrict__ x,
                                               const float* __restrict__ xmark,
                                               const float* __restrict__ ymark,
                                               const float* __restrict__ Wemb,
                                               const float* __restrict__ bemb,
                                               float* __restrict__ ws){
  __shared__ float red[256];
  __shared__ float s_sc;
  int t = threadIdx.x;
  float a = 0.f;
  if (t < CNTX) a = fabsf(x[CNTX + t]);
  red[t] = a;
  __syncthreads();
  for(int s=128; s>0; s>>=1){ if(t<s) red[t]+=red[t+s]; __syncthreads(); }
  if (t==0){ s_sc = fmaxf(red[0]/168.0f, 1e-5f); ws[WS_SC]=s_sc; }
  __syncthreads();
  float sc = s_sc;
  for(int i=t; i<HIST; i+=256) ws[WS_XS+i] = x[i]/sc;
  for(int idx=t; idx<CNTX*EMB; idx+=256){
    int tt = idx/EMB, e = idx%EMB;
    float acc = bemb[e];
    for(int f=0; f<NFEAT; f++) acc += xmark[(CNTX+tt)*NFEAT+f]*Wemb[f*EMB+e];
    ws[WS_TF+idx] = acc;
  }
  for(int idx=t; idx<PRED*EMB; idx+=256){
    int kk = idx/EMB, e = idx%EMB;
    float acc = bemb[e];
    for(int f=0; f<NFEAT; f++) acc += ymark[kk*NFEAT+f]*Wemb[f*EMB+e];
    ws[WS_YM+idx] = acc;
  }
  if (t==0){
    uint32_t* kp = reinterpret_cast<uint32_t*>(ws + WS_KEYS);
    uint32_t c0 = 0u, c1 = 42u;
    for(int k=0;k<PRED;k++){
      uint32_t a0,a1,b0,b1;
      tf_split2(c0,c1, a0,a1, b0,b1);
      c0=a0; c1=a1;
      uint32_t n0,n1,g0,g1;
      tf_split2(b0,b1, n0,n1, g0,g1);
      kp[k*4+0]=n0; kp[k*4+1]=n1; kp[k*4+2]=g0; kp[k*4+3]=g1;
    }
  }
}

// ---------------- K2: enc_gi (t<168) and gi_shared (t>=168) ----------------
__global__ __launch_bounds__(256) void k2_gi(const float* __restrict__ Wih,
                                             const float* __restrict__ bih,
                                             const float* __restrict__ bhh,
                                             float* __restrict__ ws){
  int idx = blockIdx.x*256 + threadIdx.x;
  if (idx >= 192*G3) return;
  int t = idx / G3, r = idx % G3;
  const float* wr = Wih + r*IN_DIM;
  const float* xs = ws + WS_XS;
  float acc = bih[r] + (r < 256 ? bhh[r] : 0.0f);
  if (t < CNTX){
    const float* tf = ws + WS_TF + t*EMB;
    for(int j=0;j<NLAGS;j++) acc += wr[j]*xs[CNTX + t - 1 - j];
    for(int e=0;e<EMB;e++)   acc += wr[NLAGS+e]*tf[e];
    ws[WS_ENCGI + t*G3 + r] = acc;
  } else {
    int k = t - CNTX;
    const float* ym = ws + WS_YM + k*EMB;
    for(int e=0;e<EMB;e++)   acc += wr[NLAGS+e]*ym[e];
    for(int i=k;i<NLAGS;i++) acc += wr[i]*xs[HIST-1-i+k];
    ws[WS_GISH + k*G3 + r] = acc;
  }
}

// ---------------- K2b: transpose W_ih lag cols 0..23 ----------------
__global__ __launch_bounds__(256) void k2b_wiht(const float* __restrict__ Wih,
                                                float* __restrict__ ws){
  int idx = blockIdx.x*256 + threadIdx.x;
  if (idx >= PRED*G3) return;
  int r = idx / PRED, i = idx % PRED;
  ws[WS_WIHT + i*G3 + r] = Wih[r*IN_DIM + i];
}

// ---------------- K3: encoder GRU (unchanged from passing r5/r6) ----------------
__global__ __launch_bounds__(384) void k3_enc(const float* __restrict__ Whh,
                                              const float* __restrict__ bhh,
                                              float* __restrict__ ws){
  __shared__ __align__(16) float h[HID];
  __shared__ float grz[256];
  __shared__ float hnv[HID];
  int r = threadIdx.x;
  float4 w[32];
  const float4* wr = (const float4*)(Whh + r*HID);
  #pragma unroll
  for(int i=0;i<32;i++) w[i] = wr[i];
  float bh = (r>=256)? bhh[r] : 0.0f;
  if (r < HID) h[r] = 0.0f;
  __syncthreads();
  const float* encgi = ws + WS_ENCGI;
  for(int t=0;t<CNTX;t++){
    float acc = 0.f;
    #pragma unroll
    for(int i=0;i<32;i++){
      float4 hv = *(const float4*)&h[4*i];
      float4 ww = w[i];
      acc = fmaf(ww.x,hv.x, fmaf(ww.y,hv.y, fmaf(ww.z,hv.z, fmaf(ww.w,hv.w, acc))));
    }
    if (r < 256) grz[r] = encgi[t*G3+r] + acc;
    else         hnv[r-256] = acc + bh;
    __syncthreads();
    if (r < HID){
      float rr = 1.0f/(1.0f+expf(-grz[r]));
      float zz = 1.0f/(1.0f+expf(-grz[128+r]));
      float inv = encgi[t*G3+256+r];
      float nn = tanhf(inv + rr*hnv[r]);
      h[r] = (1.0f-zz)*nn + zz*h[r];
    }
    __syncthreads();
  }
  if (r < HID) ws[WS_HLAST + r] = h[r];
}

// ---------------- K5: build Wq[q][r] = float4 W[r][4q..4q+3] (into dead ENCGI area) ----------------
__global__ __launch_bounds__(256) void k5_wq(const float* __restrict__ Whh,
                                             float* __restrict__ ws){
  int idx = blockIdx.x*256 + threadIdx.x;
  if (idx >= 32*G3) return;
  int q = idx / G3, r = idx % G3;
  float4 v = *(const float4*)&Whh[r*HID + q*4];
  ((float4*)(ws + WS_WQ))[idx] = v;
}

// ---------------- K4: decoder — 256 blocks x 1024 thr (4 waves/SIMD), SPB=32 -----------
// Thread (rg=t&127, sg=t>>7 in 0..7) owns rows {rg,128+rg,256+rg} for samples s0=4*sg..+3.
// W streamed from L2 (one stream per block, unchanged vs r10); hT4 broadcast reads;
// gates fused in-thread. Accumulation chains identical to passing r5..r10:
// init gish/bhh -> lags i-ascending -> W.h dims 4q+c ascending 0..127.
#define SPB 32
#define THR4 1024

__global__ __launch_bounds__(1024) void k4_dec(const float* __restrict__ Whh,
                                               const float* __restrict__ bhh,
                                               const float* __restrict__ Wproj,
                                               const float* __restrict__ bproj,
                                               const float* __restrict__ ws,
                                               float* __restrict__ out){
  __shared__ __align__(16) float4 hT4[128][9];   // 18.4 KB: [dim][group of 4 samples]
  __shared__ float wihT_l[24*G3];                // 36.9 KB lag weights
  __shared__ float shistT[25][34];               // 3.4 KB [k][s]
  __shared__ float parr[SPB][4];
  __shared__ float wp[HID*3];
  __shared__ float bp[3];
  __shared__ uint32_t skeys[PRED*4];

  int t = threadIdx.x;
  int b = blockIdx.x;
  int rg = t & 127;
  int sg = t >> 7;      // 0..7
  int s0 = sg*4;

  float bhn = bhh[256 + rg];

  for(int idx=t; idx<24*G3; idx+=THR4) wihT_l[idx] = ws[WS_WIHT + idx];
  for(int idx=t; idx<HID*3; idx+=THR4) wp[idx] = Wproj[idx];
  if (t < 3) bp[t] = bproj[t];
  if (t < PRED*4) skeys[t] = reinterpret_cast<const uint32_t*>(ws + WS_KEYS)[t];
  if (t < 128){
    float hl = ws[WS_HLAST + t];
    float4 v = {hl,hl,hl,hl};
    #pragma unroll
    for(int g=0;g<8;g++) hT4[t][g] = v;
  }
  float hold[4];
  {
    float hl = ws[WS_HLAST + rg];
    #pragma unroll
    for(int s=0;s<4;s++) hold[s] = hl;
  }
  float sc = ws[WS_SC];
  const float* gish = ws + WS_GISH;
  const float4* Wq4 = (const float4*)(ws + WS_WQ);
  __syncthreads();

  #pragma unroll 1
  for(int k=0;k<PRED;k++){
    // pair accumulators: p -> samples (s0+2p, s0+2p+1)
    v2f aR[2], aZ[2], aH[2], aI[2];
    {
      float gR = gish[k*G3 + rg];
      float gZ = gish[k*G3 + 128 + rg];
      float gI = gish[k*G3 + 256 + rg];
      #pragma unroll
      for(int p=0;p<2;p++){
        aR[p] = (v2f){gR,gR}; aZ[p] = (v2f){gZ,gZ};
        aI[p] = (v2f){gI,gI}; aH[p] = (v2f){bhn,bhn};
      }
    }
    // lag chains (i ascending — identical order)
    #pragma unroll 1
    for(int i=0;i<k;i++){
      float wR = wihT_l[i*G3 + rg];
      float wZ = wihT_l[i*G3 + 128 + rg];
      float wN = wihT_l[i*G3 + 256 + rg];
      v2f wR2 = {wR,wR}, wZ2 = {wZ,wZ}, wN2 = {wN,wN};
      #pragma unroll
      for(int p=0;p<2;p++){
        v2f sh = *(const v2f*)&shistT[k-1-i][s0 + 2*p];
        aR[p] = fma2(wR2, sh, aR[p]);
        aZ[p] = fma2(wZ2, sh, aZ[p]);
        aI[p] = fma2(wN2, sh, aI[p]);
      }
    }
    // main W.h: q ascending, c=0..3 -> dims ascending (identical chain)
    #pragma unroll 1
    for(int q=0;q<32;q++){
      float4 wr4 = Wq4[q*G3 + rg];
      float4 wz4 = Wq4[q*G3 + 128 + rg];
      float4 wn4 = Wq4[q*G3 + 256 + rg];
      #pragma unroll
      for(int c=0;c<4;c++){
        float wrc = (c==0)?wr4.x:(c==1)?wr4.y:(c==2)?wr4.z:wr4.w;
        float wzc = (c==0)?wz4.x:(c==1)?wz4.y:(c==2)?wz4.z:wz4.w;
        float wnc = (c==0)?wn4.x:(c==1)?wn4.y:(c==2)?wn4.z:wn4.w;
        v2f wr2 = {wrc,wrc}, wz2 = {wzc,wzc}, wn2 = {wnc,wnc};
        float4 hv = hT4[4*q + c][sg];
        v2f lo = {hv.x, hv.y}, hi = {hv.z, hv.w};
        aR[0] = fma2(wr2, lo, aR[0]);  aR[1] = fma2(wr2, hi, aR[1]);
        aZ[0] = fma2(wz2, lo, aZ[0]);  aZ[1] = fma2(wz2, hi, aZ[1]);
        aH[0] = fma2(wn2, lo, aH[0]);  aH[1] = fma2(wn2, hi, aH[1]);
      }
    }
    __syncthreads();   // all hT4 (old h) reads complete
    // gates fused in-thread (identical per-cell formulas; hold = own previous h)
    #pragma unroll
    for(int s=0;s<4;s++){
      int p = s >> 1, e = s & 1;
      float aRv = aR[p][e], aZv = aZ[p][e], aIv = aI[p][e], aHv = aH[p][e];
      float rr = 1.0f/(1.0f+expf(-aRv));
      float zz = 1.0f/(1.0f+expf(-aZv));
      float nn = tanhf(aIv + rr*aHv);
      float hn = (1.0f-zz)*nn + zz*hold[s];
      hold[s] = hn;
      ((float*)&hT4[rg][sg])[s] = hn;
    }
    __syncthreads();
    // projection: 96 threads (identical l-order); h[s][l] at word l*36+s
    if (t < SPB*3){
      int s = t/3, c2 = t%3;
      const float* hT = (const float*)hT4;
      float acc = bp[c2];
      for(int l=0;l<HID;l++) acc = fmaf(hT[l*36 + s], wp[l*3+c2], acc);
      parr[s][c2] = acc;
    }
    __syncthreads();
    // sampling: 32 threads (identical math/order)
    if (t < SPB){
      int s = t, gs = b*SPB + s;
      float p0 = parr[s][0], loc = parr[s][1], p2 = parr[s][2];
      float df = 2.0f + softplus_f(p0);
      float half_df = df*0.5f;
      float sigma = softplus_f(p2);
      uint32_t kn0 = skeys[k*4+0], kn1 = skeys[k*4+1];
      uint32_t kg0 = skeys[k*4+2], kg1 = skeys[k*4+3];
      uint32_t bnb = tf_bits_at(kn0, kn1, (uint32_t)gs);
      const float lo = -0.99999994f;
      float un = fmaxf(lo, bits_to_f01(bnb)*2.0f + lo);
      float nval = 1.41421356f * erfinv32(un);
      uint32_t gk0, gk1;
      threefry(kg0, kg1, 0u, (uint32_t)gs, gk0, gk1);
      float gmm = gamma_sample(gk0, gk1, half_df);
      float tval = nval * sqrtf(half_df / gmm);
      float samp = (loc + sigma*tval)*sc;
      out[gs*PRED + k] = samp;
      shistT[k][s] = samp / sc;
    }
    __syncthreads();
  }
}

extern "C" void kernel_launch(void* const* d_in, const int* in_sizes, int n_in,
                              void* d_out, int out_size, void* d_ws, size_t ws_size,
                              hipStream_t stream){
  const float* x     = (const float*)d_in[0];
  const float* xmark = (const float*)d_in[1];
  const float* ymark = (const float*)d_in[2];
  const float* Wemb  = (const float*)d_in[3];
  const float* bemb  = (const float*)d_in[4];
  const float* Wih   = (const float*)d_in[5];
  const float* Whh   = (const float*)d_in[6];
  const float* bih   = (const float*)d_in[7];
  const float* bhh   = (const float*)d_in[8];
  const float* Wproj = (const float*)d_in[9];
  const float* bproj = (const float*)d_in[10];
  float* ws  = (float*)d_ws;
  float* out = (float*)d_out;

  hipLaunchKernelGGL(k1_prep, dim3(1), dim3(256), 0, stream, x, xmark, ymark, Wemb, bemb, ws);
  hipLaunchKernelGGL(k2_gi, dim3(288), dim3(256), 0, stream, Wih, bih, bhh, ws);
  hipLaunchKernelGGL(k2b_wiht, dim3((PRED*G3+255)/256), dim3(256), 0, stream, Wih, ws);
  hipLaunchKernelGGL(k3_enc, dim3(1), dim3(384), 0, stream, Whh, bhh, ws);
  hipLaunchKernelGGL(k5_wq, dim3((32*G3+255)/256), dim3(256), 0, stream, Whh, ws);
  hipLaunchKernelGGL(k4_dec, dim3(NSAMP/SPB), dim3(THR4), 0, stream, Whh, bhh, Wproj, bproj, ws, out);
}

// Round 14
// 761.000 us; speedup vs baseline: 1.0623x; 1.0331x over previous
//
#include <hip/hip_runtime.h>
#include <stdint.h>

#define HIST 336
#define CNTX 168
#define PRED 24
#define HID 128
#define NFEAT 5
#define EMB 50
#define NLAGS 168
#define IN_DIM 218
#define NSAMP 8192
#define G3 384

// workspace layout (float offsets)
#define WS_XS     0
#define WS_SC     336
#define WS_TF     340
#define WS_YM     8740
#define WS_KEYS   9940
#define WS_ENCGI  10036
#define WS_WQ     10036
#define WS_GISH   74548
#define WS_HLAST  83764
#define WS_WIHT   83892

typedef float v2f __attribute__((ext_vector_type(2)));
__device__ __forceinline__ v2f fma2(v2f a, v2f b, v2f c){ return __builtin_elementwise_fma(a,b,c); }

// ---------------- threefry2x32 core (20 rounds) ----------------
__device__ __forceinline__ uint32_t rotl32(uint32_t v, int r){ return (v<<r)|(v>>(32-r)); }

__device__ __forceinline__ void threefry(uint32_t k0, uint32_t k1, uint32_t x0, uint32_t x1,
                                         uint32_t &o0, uint32_t &o1){
  uint32_t ks2 = k0 ^ k1 ^ 0x1BD11BDAu;
  x0 += k0; x1 += k1;
#define TFR(a) { x0 += x1; x1 = rotl32(x1,(a)); x1 ^= x0; }
  TFR(13) TFR(15) TFR(26) TFR(6)
  x0 += k1; x1 += ks2 + 1u;
  TFR(17) TFR(29) TFR(16) TFR(24)
  x0 += ks2; x1 += k0 + 2u;
  TFR(13) TFR(15) TFR(26) TFR(6)
  x0 += k0; x1 += k1 + 3u;
  TFR(17) TFR(29) TFR(16) TFR(24)
  x0 += k1; x1 += ks2 + 4u;
  TFR(13) TFR(15) TFR(26) TFR(6)
  x0 += ks2; x1 += k0 + 5u;
#undef TFR
  o0 = x0; o1 = x1;
}

// ---------------- partitionable (foldlike) JAX PRNG semantics ----------------
__device__ __forceinline__ void tf_split2(uint32_t k0, uint32_t k1,
                                          uint32_t &a0, uint32_t &a1,
                                          uint32_t &b0, uint32_t &b1){
  threefry(k0,k1, 0u,0u, a0,a1);
  threefry(k0,k1, 0u,1u, b0,b1);
}

__device__ __forceinline__ void tf_split3(uint32_t k0, uint32_t k1,
                                          uint32_t &a0, uint32_t &a1,
                                          uint32_t &b0, uint32_t &b1,
                                          uint32_t &c0, uint32_t &c1){
  threefry(k0,k1, 0u,0u, a0,a1);
  threefry(k0,k1, 0u,1u, b0,b1);
  threefry(k0,k1, 0u,2u, c0,c1);
}

__device__ __forceinline__ uint32_t tf_bits1(uint32_t k0, uint32_t k1){
  uint32_t o0,o1; threefry(k0,k1, 0u,0u, o0,o1); return o0 ^ o1;
}

__device__ __forceinline__ uint32_t tf_bits_at(uint32_t k0, uint32_t k1, uint32_t i){
  uint32_t o0,o1; threefry(k0,k1, 0u,i, o0,o1); return o0 ^ o1;
}

__device__ __forceinline__ float bits_to_f01(uint32_t b){
  return __uint_as_float((b>>9) | 0x3f800000u) - 1.0f;
}

// XLA ErfInv32 polynomial
__device__ __forceinline__ float erfinv32(float x){
  float w = -log1pf(-x*x);
  float p;
  if (w < 5.0f){
    w = w - 2.5f;
    p = 2.81022636e-08f;
    p = fmaf(p, w, 3.43273939e-07f);
    p = fmaf(p, w, -3.5233877e-06f);
    p = fmaf(p, w, -4.39150654e-06f);
    p = fmaf(p, w, 0.00021858087f);
    p = fmaf(p, w, -0.00125372503f);
    p = fmaf(p, w, -0.00417768164f);
    p = fmaf(p, w, 0.246640727f);
    p = fmaf(p, w, 1.50140941f);
  } else {
    w = sqrtf(w) - 3.0f;
    p = -0.000200214257f;
    p = fmaf(p, w, 0.000100950558f);
    p = fmaf(p, w, 0.00134934322f);
    p = fmaf(p, w, -0.00367342844f);
    p = fmaf(p, w, 0.00573950773f);
    p = fmaf(p, w, -0.0076224613f);
    p = fmaf(p, w, 0.00943887047f);
    p = fmaf(p, w, 1.00167406f);
    p = fmaf(p, w, 2.83297682f);
  }
  return p*x;
}

__device__ __forceinline__ float normal_from_key(uint32_t k0, uint32_t k1){
  uint32_t b = tf_bits1(k0,k1);
  const float lo = -0.99999994f;
  float f = bits_to_f01(b);
  float u = fmaxf(lo, f*2.0f + lo);
  return 1.41421356f * erfinv32(u);
}

// JAX _gamma_one, alpha >= 1 branch (boost==1)
__device__ float gamma_sample(uint32_t k0, uint32_t k1, float alpha){
  float d = __fsub_rn(alpha, 0.33333334f);
  float c = 0.33333334f / sqrtf(d);
  uint32_t ck0,ck1, sb0,sb1;
  tf_split2(k0,k1, ck0,ck1, sb0,sb1);
  float V;
  for(;;){
    uint32_t nk0,nk1, xk0,xk1, uk0,uk1;
    tf_split3(ck0,ck1, nk0,nk1, xk0,xk1, uk0,uk1);
    ck0=nk0; ck1=nk1;
    float x, v;
    do {
      uint32_t xa0,xa1, xb0,xb1;
      tf_split2(xk0,xk1, xa0,xa1, xb0,xb1);
      xk0=xa0; xk1=xa1;
      x = normal_from_key(xb0,xb1);
      v = __fadd_rn(1.0f, __fmul_rn(x, c));
    } while (v <= 0.0f);
    float X  = __fmul_rn(x, x);
    float Vv = __fmul_rn(__fmul_rn(v, v), v);
    float U  = bits_to_f01(tf_bits1(uk0,uk1));
    float t1 = __fsub_rn(1.0f, __fmul_rn(0.0331f, __fmul_rn(X, X)));
    bool cont = (U >= t1);
    if (cont){
      float lhs = logf(U);
      float rhs = __fadd_rn(__fmul_rn(0.5f, X),
                  __fmul_rn(d, __fadd_rn(__fsub_rn(1.0f, Vv), logf(Vv))));
      cont = (lhs >= rhs);
    }
    if (!cont){ V = Vv; break; }
  }
  return d*V;
}

__device__ __forceinline__ float softplus_f(float x){
  float amax = fmaxf(x, 0.0f);
  return amax + log1pf(expf(-fabsf(x)));
}

// ---------------- K1: scale, xs, tf, ym, step keys ----------------
__global__ __launch_bounds__(256) void k1_prep(const float* __restrict__ x,
                                               const float* __restrict__ xmark,
                                               const float* __restrict__ ymark,
                                               const float* __restrict__ Wemb,
                                               const float* __restrict__ bemb,
                                               float* __restrict__ ws){
  __shared__ float red[256];
  __shared__ float s_sc;
  int t = threadIdx.x;
  float a = 0.f;
  if (t < CNTX) a = fabsf(x[CNTX + t]);
  red[t] = a;
  __syncthreads();
  for(int s=128; s>0; s>>=1){ if(t<s) red[t]+=red[t+s]; __syncthreads(); }
  if (t==0){ s_sc = fmaxf(red[0]/168.0f, 1e-5f); ws[WS_SC]=s_sc; }
  __syncthreads();
  float sc = s_sc;
  for(int i=t; i<HIST; i+=256) ws[WS_XS+i] = x[i]/sc;
  for(int idx=t; idx<CNTX*EMB; idx+=256){
    int tt = idx/EMB, e = idx%EMB;
    float acc = bemb[e];
    for(int f=0; f<NFEAT; f++) acc += xmark[(CNTX+tt)*NFEAT+f]*Wemb[f*EMB+e];
    ws[WS_TF+idx] = acc;
  }
  for(int idx=t; idx<PRED*EMB; idx+=256){
    int kk = idx/EMB, e = idx%EMB;
    float acc = bemb[e];
    for(int f=0; f<NFEAT; f++) acc += ymark[kk*NFEAT+f]*Wemb[f*EMB+e];
    ws[WS_YM+idx] = acc;
  }
  if (t==0){
    uint32_t* kp = reinterpret_cast<uint32_t*>(ws + WS_KEYS);
    uint32_t c0 = 0u, c1 = 42u;
    for(int k=0;k<PRED;k++){
      uint32_t a0,a1,b0,b1;
      tf_split2(c0,c1, a0,a1, b0,b1);
      c0=a0; c1=a1;
      uint32_t n0,n1,g0,g1;
      tf_split2(b0,b1, n0,n1, g0,g1);
      kp[k*4+0]=n0; kp[k*4+1]=n1; kp[k*4+2]=g0; kp[k*4+3]=g1;
    }
  }
}

// ---------------- K2: enc_gi (t<168) and gi_shared (t>=168) ----------------
__global__ __launch_bounds__(256) void k2_gi(const float* __restrict__ Wih,
                                             const float* __restrict__ bih,
                                             const float* __restrict__ bhh,
                                             float* __restrict__ ws){
  int idx = blockIdx.x*256 + threadIdx.x;
  if (idx >= 192*G3) return;
  int t = idx / G3, r = idx % G3;
  const float* wr = Wih + r*IN_DIM;
  const float* xs = ws + WS_XS;
  float acc = bih[r] + (r < 256 ? bhh[r] : 0.0f);
  if (t < CNTX){
    const float* tf = ws + WS_TF + t*EMB;
    for(int j=0;j<NLAGS;j++) acc += wr[j]*xs[CNTX + t - 1 - j];
    for(int e=0;e<EMB;e++)   acc += wr[NLAGS+e]*tf[e];
    ws[WS_ENCGI + t*G3 + r] = acc;
  } else {
    int k = t - CNTX;
    const float* ym = ws + WS_YM + k*EMB;
    for(int e=0;e<EMB;e++)   acc += wr[NLAGS+e]*ym[e];
    for(int i=k;i<NLAGS;i++) acc += wr[i]*xs[HIST-1-i+k];
    ws[WS_GISH + k*G3 + r] = acc;
  }
}

// ---------------- K2b: transpose W_ih lag cols 0..23 ----------------
__global__ __launch_bounds__(256) void k2b_wiht(const float* __restrict__ Wih,
                                                float* __restrict__ ws){
  int idx = blockIdx.x*256 + threadIdx.x;
  if (idx >= PRED*G3) return;
  int r = idx / PRED, i = idx % PRED;
  ws[WS_WIHT + i*G3 + r] = Wih[r*IN_DIM + i];
}

// ---------------- K3: encoder GRU (unchanged from passing r5/r6) ----------------
__global__ __launch_bounds__(384) void k3_enc(const float* __restrict__ Whh,
                                              const float* __restrict__ bhh,
                                              float* __restrict__ ws){
  __shared__ __align__(16) float h[HID];
  __shared__ float grz[256];
  __shared__ float hnv[HID];
  int r = threadIdx.x;
  float4 w[32];
  const float4* wr = (const float4*)(Whh + r*HID);
  #pragma unroll
  for(int i=0;i<32;i++) w[i] = wr[i];
  float bh = (r>=256)? bhh[r] : 0.0f;
  if (r < HID) h[r] = 0.0f;
  __syncthreads();
  const float* encgi = ws + WS_ENCGI;
  for(int t=0;t<CNTX;t++){
    float acc = 0.f;
    #pragma unroll
    for(int i=0;i<32;i++){
      float4 hv = *(const float4*)&h[4*i];
      float4 ww = w[i];
      acc = fmaf(ww.x,hv.x, fmaf(ww.y,hv.y, fmaf(ww.z,hv.z, fmaf(ww.w,hv.w, acc))));
    }
    if (r < 256) grz[r] = encgi[t*G3+r] + acc;
    else         hnv[r-256] = acc + bh;
    __syncthreads();
    if (r < HID){
      float rr = 1.0f/(1.0f+expf(-grz[r]));
      float zz = 1.0f/(1.0f+expf(-grz[128+r]));
      float inv = encgi[t*G3+256+r];
      float nn = tanhf(inv + rr*hnv[r]);
      h[r] = (1.0f-zz)*nn + zz*h[r];
    }
    __syncthreads();
  }
  if (r < HID) ws[WS_HLAST + r] = h[r];
}

// ---------------- K5: build Wq[q][r] = float4 W[r][4q..4q+3] (into dead ENCGI area) ----------------
__global__ __launch_bounds__(256) void k5_wq(const float* __restrict__ Whh,
                                             float* __restrict__ ws){
  int idx = blockIdx.x*256 + threadIdx.x;
  if (idx >= 32*G3) return;
  int q = idx / G3, r = idx % G3;
  float4 v = *(const float4*)&Whh[r*HID + q*4];
  ((float4*)(ws + WS_WQ))[idx] = v;
}

// ---------------- K4: decoder — r10 config + distance-1 W prefetch ----------------
// 256 blocks x 512 threads. Thread (rg=t&127, sg=t>>7) owns rows {rg,128+rg,256+rg} and
// samples s0=8*sg..+7. Gates fused in-thread. Accumulation chains identical to r5..r13:
// init gish/bhh -> lags i-ascending -> W.h dims 4q+c ascending 0..127.
#define SPB 32
#define THR4 512

__global__ __launch_bounds__(512) void k4_dec(const float* __restrict__ Whh,
                                              const float* __restrict__ bhh,
                                              const float* __restrict__ Wproj,
                                              const float* __restrict__ bproj,
                                              const float* __restrict__ ws,
                                              float* __restrict__ out){
  __shared__ __align__(16) float4 hT4[128][9];   // 18.4 KB
  __shared__ float wihT_l[24*G3];                // 36.9 KB
  __shared__ float shistT[25][34];               // 3.4 KB
  __shared__ float parr[SPB][4];
  __shared__ float wp[HID*3];
  __shared__ float bp[3];
  __shared__ uint32_t skeys[PRED*4];

  int t = threadIdx.x;
  int b = blockIdx.x;
  int rg = t & 127;
  int sg = t >> 7;      // 0..3
  int s0 = sg*8;
  int g0 = sg*2;

  float bhn = bhh[256 + rg];

  for(int idx=t; idx<24*G3; idx+=THR4) wihT_l[idx] = ws[WS_WIHT + idx];
  for(int idx=t; idx<HID*3; idx+=THR4) wp[idx] = Wproj[idx];
  if (t < 3) bp[t] = bproj[t];
  if (t < PRED*4) skeys[t] = reinterpret_cast<const uint32_t*>(ws + WS_KEYS)[t];
  if (t < 128){
    float hl = ws[WS_HLAST + t];
    float4 v = {hl,hl,hl,hl};
    #pragma unroll
    for(int g=0;g<8;g++) hT4[t][g] = v;
  }
  float hold[8];
  {
    float hl = ws[WS_HLAST + rg];
    #pragma unroll
    for(int s=0;s<8;s++) hold[s] = hl;
  }
  float sc = ws[WS_SC];
  const float* gish = ws + WS_GISH;
  const float4* Wq4 = (const float4*)(ws + WS_WQ);
  __syncthreads();

  #pragma unroll 1
  for(int k=0;k<PRED;k++){
    v2f aR[4], aZ[4], aH[4], aI[4];
    {
      float gR = gish[k*G3 + rg];
      float gZ = gish[k*G3 + 128 + rg];
      float gI = gish[k*G3 + 256 + rg];
      #pragma unroll
      for(int p=0;p<4;p++){
        aR[p] = (v2f){gR,gR}; aZ[p] = (v2f){gZ,gZ};
        aI[p] = (v2f){gI,gI}; aH[p] = (v2f){bhn,bhn};
      }
    }
    // lag chains (i ascending — identical order)
    #pragma unroll 1
    for(int i=0;i<k;i++){
      float wR = wihT_l[i*G3 + rg];
      float wZ = wihT_l[i*G3 + 128 + rg];
      float wN = wihT_l[i*G3 + 256 + rg];
      v2f wR2 = {wR,wR}, wZ2 = {wZ,wZ}, wN2 = {wN,wN};
      #pragma unroll
      for(int p=0;p<4;p++){
        v2f sh = *(const v2f*)&shistT[k-1-i][s0 + 2*p];
        aR[p] = fma2(wR2, sh, aR[p]);
        aZ[p] = fma2(wZ2, sh, aZ[p]);
        aI[p] = fma2(wN2, sh, aI[p]);
      }
    }
    // main W.h: distance-1 prefetch; dims 4q+c ascending (identical chain to r10)
    {
      float4 wr4 = Wq4[0*G3 + rg];
      float4 wz4 = Wq4[0*G3 + 128 + rg];
      float4 wn4 = Wq4[0*G3 + 256 + rg];
      #pragma unroll 1
      for(int q=0;q<32;q++){
        float4 nr, nz, nn_;
        if (q < 31){
          nr  = Wq4[(q+1)*G3 + rg];
          nz  = Wq4[(q+1)*G3 + 128 + rg];
          nn_ = Wq4[(q+1)*G3 + 256 + rg];
        }
        #pragma unroll
        for(int c=0;c<4;c++){
          float wrc = (c==0)?wr4.x:(c==1)?wr4.y:(c==2)?wr4.z:wr4.w;
          float wzc = (c==0)?wz4.x:(c==1)?wz4.y:(c==2)?wz4.z:wz4.w;
          float wnc = (c==0)?wn4.x:(c==1)?wn4.y:(c==2)?wn4.z:wn4.w;
          v2f wr2 = {wrc,wrc}, wz2 = {wzc,wzc}, wn2 = {wnc,wnc};
          #pragma unroll
          for(int g=0;g<2;g++){
            float4 hv = hT4[4*q + c][g0 + g];
            v2f lo = {hv.x, hv.y}, hi = {hv.z, hv.w};
            aR[2*g]   = fma2(wr2, lo, aR[2*g]);
            aR[2*g+1] = fma2(wr2, hi, aR[2*g+1]);
            aZ[2*g]   = fma2(wz2, lo, aZ[2*g]);
            aZ[2*g+1] = fma2(wz2, hi, aZ[2*g+1]);
            aH[2*g]   = fma2(wn2, lo, aH[2*g]);
            aH[2*g+1] = fma2(wn2, hi, aH[2*g+1]);
          }
        }
        wr4 = nr; wz4 = nz; wn4 = nn_;
      }
    }
    __syncthreads();   // all hT4 (old h) reads complete
    // gates fused in-thread (identical per-cell formulas)
    #pragma unroll
    for(int s=0;s<8;s++){
      int p = s >> 1, e = s & 1;
      float aRv = aR[p][e], aZv = aZ[p][e], aIv = aI[p][e], aHv = aH[p][e];
      float rr = 1.0f/(1.0f+expf(-aRv));
      float zz = 1.0f/(1.0f+expf(-aZv));
      float nn = tanhf(aIv + rr*aHv);
      float hn = (1.0f-zz)*nn + zz*hold[s];
      hold[s] = hn;
      ((float*)&hT4[rg][g0 + (s>>2)])[s & 3] = hn;
    }
    __syncthreads();
    // projection: 96 threads (identical l-order); h[s][l] at word l*36+s
    if (t < SPB*3){
      int s = t/3, c2 = t%3;
      const float* hT = (const float*)hT4;
      float acc = bp[c2];
      for(int l=0;l<HID;l++) acc = fmaf(hT[l*36 + s], wp[l*3+c2], acc);
      parr[s][c2] = acc;
    }
    __syncthreads();
    // sampling: 32 threads (identical math/order)
    if (t < SPB){
      int s = t, gs = b*SPB + s;
      float p0 = parr[s][0], loc = parr[s][1], p2 = parr[s][2];
      float df = 2.0f + softplus_f(p0);
      float half_df = df*0.5f;
      float sigma = softplus_f(p2);
      uint32_t kn0 = skeys[k*4+0], kn1 = skeys[k*4+1];
      uint32_t kg0 = skeys[k*4+2], kg1 = skeys[k*4+3];
      uint32_t bnb = tf_bits_at(kn0, kn1, (uint32_t)gs);
      const float lo = -0.99999994f;
      float un = fmaxf(lo, bits_to_f01(bnb)*2.0f + lo);
      float nval = 1.41421356f * erfinv32(un);
      uint32_t gk0, gk1;
      threefry(kg0, kg1, 0u, (uint32_t)gs, gk0, gk1);
      float gmm = gamma_sample(gk0, gk1, half_df);
      float tval = nval * sqrtf(half_df / gmm);
      float samp = (loc + sigma*tval)*sc;
      out[gs*PRED + k] = samp;
      shistT[k][s] = samp / sc;
    }
    __syncthreads();
  }
}

extern "C" void kernel_launch(void* const* d_in, const int* in_sizes, int n_in,
                              void* d_out, int out_size, void* d_ws, size_t ws_size,
                              hipStream_t stream){
  const float* x     = (const float*)d_in[0];
  const float* xmark = (const float*)d_in[1];
  const float* ymark = (const float*)d_in[2];
  const float* Wemb  = (const float*)d_in[3];
  const float* bemb  = (const float*)d_in[4];
  const float* Wih   = (const float*)d_in[5];
  const float* Whh   = (const float*)d_in[6];
  const float* bih   = (const float*)d_in[7];
  const float* bhh   = (const float*)d_in[8];
  const float* Wproj = (const float*)d_in[9];
  const float* bproj = (const float*)d_in[10];
  float* ws  = (float*)d_ws;
  float* out = (float*)d_out;

  hipLaunchKernelGGL(k1_prep, dim3(1), dim3(256), 0, stream, x, xmark, ymark, Wemb, bemb, ws);
  hipLaunchKernelGGL(k2_gi, dim3(288), dim3(256), 0, stream, Wih, bih, bhh, ws);
  hipLaunchKernelGGL(k2b_wiht, dim3((PRED*G3+255)/256), dim3(256), 0, stream, Wih, ws);
  hipLaunchKernelGGL(k3_enc, dim3(1), dim3(384), 0, stream, Whh, bhh, ws);
  hipLaunchKernelGGL(k5_wq, dim3((32*G3+255)/256), dim3(256), 0, stream, Whh, ws);
  hipLaunchKernelGGL(k4_dec, dim3(NSAMP/SPB), dim3(THR4), 0, stream, Whh, bhh, Wproj, bproj, ws, out);
}

// Round 15
// 753.457 us; speedup vs baseline: 1.0730x; 1.0100x over previous
//
#include <hip/hip_runtime.h>
#include <stdint.h>

#define HIST 336
#define CNTX 168
#define PRED 24
#define HID 128
#define NFEAT 5
#define EMB 50
#define NLAGS 168
#define IN_DIM 218
#define NSAMP 8192
#define G3 384

// workspace layout (float offsets)
#define WS_XS     0
#define WS_SC     336
#define WS_TF     340
#define WS_YM     8740
#define WS_KEYS   9940
#define WS_ENCGI  10036
#define WS_WQ     10036
#define WS_GISH   74548
#define WS_HLAST  83764
#define WS_WIHT   83892

typedef float v2f __attribute__((ext_vector_type(2)));
__device__ __forceinline__ v2f fma2(v2f a, v2f b, v2f c){ return __builtin_elementwise_fma(a,b,c); }

// ---------------- threefry2x32 core (20 rounds) ----------------
__device__ __forceinline__ uint32_t rotl32(uint32_t v, int r){ return (v<<r)|(v>>(32-r)); }

__device__ __forceinline__ void threefry(uint32_t k0, uint32_t k1, uint32_t x0, uint32_t x1,
                                         uint32_t &o0, uint32_t &o1){
  uint32_t ks2 = k0 ^ k1 ^ 0x1BD11BDAu;
  x0 += k0; x1 += k1;
#define TFR(a) { x0 += x1; x1 = rotl32(x1,(a)); x1 ^= x0; }
  TFR(13) TFR(15) TFR(26) TFR(6)
  x0 += k1; x1 += ks2 + 1u;
  TFR(17) TFR(29) TFR(16) TFR(24)
  x0 += ks2; x1 += k0 + 2u;
  TFR(13) TFR(15) TFR(26) TFR(6)
  x0 += k0; x1 += k1 + 3u;
  TFR(17) TFR(29) TFR(16) TFR(24)
  x0 += k1; x1 += ks2 + 4u;
  TFR(13) TFR(15) TFR(26) TFR(6)
  x0 += ks2; x1 += k0 + 5u;
#undef TFR
  o0 = x0; o1 = x1;
}

// ---------------- partitionable (foldlike) JAX PRNG semantics ----------------
__device__ __forceinline__ void tf_split2(uint32_t k0, uint32_t k1,
                                          uint32_t &a0, uint32_t &a1,
                                          uint32_t &b0, uint32_t &b1){
  threefry(k0,k1, 0u,0u, a0,a1);
  threefry(k0,k1, 0u,1u, b0,b1);
}

__device__ __forceinline__ void tf_split3(uint32_t k0, uint32_t k1,
                                          uint32_t &a0, uint32_t &a1,
                                          uint32_t &b0, uint32_t &b1,
                                          uint32_t &c0, uint32_t &c1){
  threefry(k0,k1, 0u,0u, a0,a1);
  threefry(k0,k1, 0u,1u, b0,b1);
  threefry(k0,k1, 0u,2u, c0,c1);
}

__device__ __forceinline__ uint32_t tf_bits1(uint32_t k0, uint32_t k1){
  uint32_t o0,o1; threefry(k0,k1, 0u,0u, o0,o1); return o0 ^ o1;
}

__device__ __forceinline__ uint32_t tf_bits_at(uint32_t k0, uint32_t k1, uint32_t i){
  uint32_t o0,o1; threefry(k0,k1, 0u,i, o0,o1); return o0 ^ o1;
}

__device__ __forceinline__ float bits_to_f01(uint32_t b){
  return __uint_as_float((b>>9) | 0x3f800000u) - 1.0f;
}

// XLA ErfInv32 polynomial
__device__ __forceinline__ float erfinv32(float x){
  float w = -log1pf(-x*x);
  float p;
  if (w < 5.0f){
    w = w - 2.5f;
    p = 2.81022636e-08f;
    p = fmaf(p, w, 3.43273939e-07f);
    p = fmaf(p, w, -3.5233877e-06f);
    p = fmaf(p, w, -4.39150654e-06f);
    p = fmaf(p, w, 0.00021858087f);
    p = fmaf(p, w, -0.00125372503f);
    p = fmaf(p, w, -0.00417768164f);
    p = fmaf(p, w, 0.246640727f);
    p = fmaf(p, w, 1.50140941f);
  } else {
    w = sqrtf(w) - 3.0f;
    p = -0.000200214257f;
    p = fmaf(p, w, 0.000100950558f);
    p = fmaf(p, w, 0.00134934322f);
    p = fmaf(p, w, -0.00367342844f);
    p = fmaf(p, w, 0.00573950773f);
    p = fmaf(p, w, -0.0076224613f);
    p = fmaf(p, w, 0.00943887047f);
    p = fmaf(p, w, 1.00167406f);
    p = fmaf(p, w, 2.83297682f);
  }
  return p*x;
}

__device__ __forceinline__ float normal_from_key(uint32_t k0, uint32_t k1){
  uint32_t b = tf_bits1(k0,k1);
  const float lo = -0.99999994f;
  float f = bits_to_f01(b);
  float u = fmaxf(lo, f*2.0f + lo);
  return 1.41421356f * erfinv32(u);
}

// JAX _gamma_one, alpha >= 1 branch (boost==1)
__device__ float gamma_sample(uint32_t k0, uint32_t k1, float alpha){
  float d = __fsub_rn(alpha, 0.33333334f);
  float c = 0.33333334f / sqrtf(d);
  uint32_t ck0,ck1, sb0,sb1;
  tf_split2(k0,k1, ck0,ck1, sb0,sb1);
  float V;
  for(;;){
    uint32_t nk0,nk1, xk0,xk1, uk0,uk1;
    tf_split3(ck0,ck1, nk0,nk1, xk0,xk1, uk0,uk1);
    ck0=nk0; ck1=nk1;
    float x, v;
    do {
      uint32_t xa0,xa1, xb0,xb1;
      tf_split2(xk0,xk1, xa0,xa1, xb0,xb1);
      xk0=xa0; xk1=xa1;
      x = normal_from_key(xb0,xb1);
      v = __fadd_rn(1.0f, __fmul_rn(x, c));
    } while (v <= 0.0f);
    float X  = __fmul_rn(x, x);
    float Vv = __fmul_rn(__fmul_rn(v, v), v);
    float U  = bits_to_f01(tf_bits1(uk0,uk1));
    float t1 = __fsub_rn(1.0f, __fmul_rn(0.0331f, __fmul_rn(X, X)));
    bool cont = (U >= t1);
    if (cont){
      float lhs = logf(U);
      float rhs = __fadd_rn(__fmul_rn(0.5f, X),
                  __fmul_rn(d, __fadd_rn(__fsub_rn(1.0f, Vv), logf(Vv))));
      cont = (lhs >= rhs);
    }
    if (!cont){ V = Vv; break; }
  }
  return d*V;
}

__device__ __forceinline__ float softplus_f(float x){
  float amax = fmaxf(x, 0.0f);
  return amax + log1pf(expf(-fabsf(x)));
}

// ---------------- K1: scale, xs, tf, ym, step keys ----------------
__global__ __launch_bounds__(256) void k1_prep(const float* __restrict__ x,
                                               const float* __restrict__ xmark,
                                               const float* __restrict__ ymark,
                                               const float* __restrict__ Wemb,
                                               const float* __restrict__ bemb,
                                               float* __restrict__ ws){
  __shared__ float red[256];
  __shared__ float s_sc;
  int t = threadIdx.x;
  float a = 0.f;
  if (t < CNTX) a = fabsf(x[CNTX + t]);
  red[t] = a;
  __syncthreads();
  for(int s=128; s>0; s>>=1){ if(t<s) red[t]+=red[t+s]; __syncthreads(); }
  if (t==0){ s_sc = fmaxf(red[0]/168.0f, 1e-5f); ws[WS_SC]=s_sc; }
  __syncthreads();
  float sc = s_sc;
  for(int i=t; i<HIST; i+=256) ws[WS_XS+i] = x[i]/sc;
  for(int idx=t; idx<CNTX*EMB; idx+=256){
    int tt = idx/EMB, e = idx%EMB;
    float acc = bemb[e];
    for(int f=0; f<NFEAT; f++) acc += xmark[(CNTX+tt)*NFEAT+f]*Wemb[f*EMB+e];
    ws[WS_TF+idx] = acc;
  }
  for(int idx=t; idx<PRED*EMB; idx+=256){
    int kk = idx/EMB, e = idx%EMB;
    float acc = bemb[e];
    for(int f=0; f<NFEAT; f++) acc += ymark[kk*NFEAT+f]*Wemb[f*EMB+e];
    ws[WS_YM+idx] = acc;
  }
  if (t==0){
    uint32_t* kp = reinterpret_cast<uint32_t*>(ws + WS_KEYS);
    uint32_t c0 = 0u, c1 = 42u;
    for(int k=0;k<PRED;k++){
      uint32_t a0,a1,b0,b1;
      tf_split2(c0,c1, a0,a1, b0,b1);
      c0=a0; c1=a1;
      uint32_t n0,n1,g0,g1;
      tf_split2(b0,b1, n0,n1, g0,g1);
      kp[k*4+0]=n0; kp[k*4+1]=n1; kp[k*4+2]=g0; kp[k*4+3]=g1;
    }
  }
}

// ---------------- K2: enc_gi (t<168) and gi_shared (t>=168) ----------------
__global__ __launch_bounds__(256) void k2_gi(const float* __restrict__ Wih,
                                             const float* __restrict__ bih,
                                             const float* __restrict__ bhh,
                                             float* __restrict__ ws){
  int idx = blockIdx.x*256 + threadIdx.x;
  if (idx >= 192*G3) return;
  int t = idx / G3, r = idx % G3;
  const float* wr = Wih + r*IN_DIM;
  const float* xs = ws + WS_XS;
  float acc = bih[r] + (r < 256 ? bhh[r] : 0.0f);
  if (t < CNTX){
    const float* tf = ws + WS_TF + t*EMB;
    for(int j=0;j<NLAGS;j++) acc += wr[j]*xs[CNTX + t - 1 - j];
    for(int e=0;e<EMB;e++)   acc += wr[NLAGS+e]*tf[e];
    ws[WS_ENCGI + t*G3 + r] = acc;
  } else {
    int k = t - CNTX;
    const float* ym = ws + WS_YM + k*EMB;
    for(int e=0;e<EMB;e++)   acc += wr[NLAGS+e]*ym[e];
    for(int i=k;i<NLAGS;i++) acc += wr[i]*xs[HIST-1-i+k];
    ws[WS_GISH + k*G3 + r] = acc;
  }
}

// ---------------- K2b: transpose W_ih lag cols 0..23 ----------------
__global__ __launch_bounds__(256) void k2b_wiht(const float* __restrict__ Wih,
                                                float* __restrict__ ws){
  int idx = blockIdx.x*256 + threadIdx.x;
  if (idx >= PRED*G3) return;
  int r = idx / PRED, i = idx % PRED;
  ws[WS_WIHT + i*G3 + r] = Wih[r*IN_DIM + i];
}

// ---------------- K3: encoder GRU (unchanged from passing r5/r6) ----------------
__global__ __launch_bounds__(384) void k3_enc(const float* __restrict__ Whh,
                                              const float* __restrict__ bhh,
                                              float* __restrict__ ws){
  __shared__ __align__(16) float h[HID];
  __shared__ float grz[256];
  __shared__ float hnv[HID];
  int r = threadIdx.x;
  float4 w[32];
  const float4* wr = (const float4*)(Whh + r*HID);
  #pragma unroll
  for(int i=0;i<32;i++) w[i] = wr[i];
  float bh = (r>=256)? bhh[r] : 0.0f;
  if (r < HID) h[r] = 0.0f;
  __syncthreads();
  const float* encgi = ws + WS_ENCGI;
  for(int t=0;t<CNTX;t++){
    float acc = 0.f;
    #pragma unroll
    for(int i=0;i<32;i++){
      float4 hv = *(const float4*)&h[4*i];
      float4 ww = w[i];
      acc = fmaf(ww.x,hv.x, fmaf(ww.y,hv.y, fmaf(ww.z,hv.z, fmaf(ww.w,hv.w, acc))));
    }
    if (r < 256) grz[r] = encgi[t*G3+r] + acc;
    else         hnv[r-256] = acc + bh;
    __syncthreads();
    if (r < HID){
      float rr = 1.0f/(1.0f+expf(-grz[r]));
      float zz = 1.0f/(1.0f+expf(-grz[128+r]));
      float inv = encgi[t*G3+256+r];
      float nn = tanhf(inv + rr*hnv[r]);
      h[r] = (1.0f-zz)*nn + zz*h[r];
    }
    __syncthreads();
  }
  if (r < HID) ws[WS_HLAST + r] = h[r];
}

// ---------------- K5: build Wq[q][r] = float4 W[r][4q..4q+3] (into dead ENCGI area) ----------------
__global__ __launch_bounds__(256) void k5_wq(const float* __restrict__ Whh,
                                             float* __restrict__ ws){
  int idx = blockIdx.x*256 + threadIdx.x;
  if (idx >= 32*G3) return;
  int q = idx / G3, r = idx % G3;
  float4 v = *(const float4*)&Whh[r*HID + q*4];
  ((float4*)(ws + WS_WQ))[idx] = v;
}

// ---------------- K4: decoder — r10 structure; W half staged in LDS (grid=1 block/CU) ----
// 256 blocks x 512 threads. Thread (rg=t&127, sg=t>>7) owns rows {rg,128+rg,256+rg} and
// samples s0=8*sg..+7. Gates fused in-thread. q<16 W from LDS, q>=16 streamed from L2.
// Accumulation chains identical to r5..r14: init gish/bhh -> lags i-ascending ->
// W.h dims 4q+c ascending 0..127.
#define SPB 32
#define THR4 512
#define QLDS 16

__global__ __launch_bounds__(512) void k4_dec(const float* __restrict__ Whh,
                                              const float* __restrict__ bhh,
                                              const float* __restrict__ Wproj,
                                              const float* __restrict__ bproj,
                                              const float* __restrict__ ws,
                                              float* __restrict__ out){
  __shared__ __align__(16) float4 wlds[QLDS*G3]; // 98.3 KB: Wq[q][r] for q<16
  __shared__ __align__(16) float4 hT4[128][9];   // 18.4 KB
  __shared__ float wihT_l[24*G3];                // 36.9 KB
  __shared__ float shistT[25][34];               // 3.4 KB
  __shared__ float parr[SPB][4];
  __shared__ float wp[HID*3];
  __shared__ float bp[3];
  __shared__ uint32_t skeys[PRED*4];

  int t = threadIdx.x;
  int b = blockIdx.x;
  int rg = t & 127;
  int sg = t >> 7;      // 0..3
  int s0 = sg*8;
  int g0 = sg*2;

  float bhn = bhh[256 + rg];
  const float4* Wq4 = (const float4*)(ws + WS_WQ);

  for(int idx=t; idx<QLDS*G3; idx+=THR4) wlds[idx] = Wq4[idx];
  for(int idx=t; idx<24*G3; idx+=THR4) wihT_l[idx] = ws[WS_WIHT + idx];
  for(int idx=t; idx<HID*3; idx+=THR4) wp[idx] = Wproj[idx];
  if (t < 3) bp[t] = bproj[t];
  if (t < PRED*4) skeys[t] = reinterpret_cast<const uint32_t*>(ws + WS_KEYS)[t];
  if (t < 128){
    float hl = ws[WS_HLAST + t];
    float4 v = {hl,hl,hl,hl};
    #pragma unroll
    for(int g=0;g<8;g++) hT4[t][g] = v;
  }
  float hold[8];
  {
    float hl = ws[WS_HLAST + rg];
    #pragma unroll
    for(int s=0;s<8;s++) hold[s] = hl;
  }
  float sc = ws[WS_SC];
  const float* gish = ws + WS_GISH;
  __syncthreads();

  #pragma unroll 1
  for(int k=0;k<PRED;k++){
    v2f aR[4], aZ[4], aH[4], aI[4];
    {
      float gR = gish[k*G3 + rg];
      float gZ = gish[k*G3 + 128 + rg];
      float gI = gish[k*G3 + 256 + rg];
      #pragma unroll
      for(int p=0;p<4;p++){
        aR[p] = (v2f){gR,gR}; aZ[p] = (v2f){gZ,gZ};
        aI[p] = (v2f){gI,gI}; aH[p] = (v2f){bhn,bhn};
      }
    }
    // lag chains (i ascending — identical order)
    #pragma unroll 1
    for(int i=0;i<k;i++){
      float wR = wihT_l[i*G3 + rg];
      float wZ = wihT_l[i*G3 + 128 + rg];
      float wN = wihT_l[i*G3 + 256 + rg];
      v2f wR2 = {wR,wR}, wZ2 = {wZ,wZ}, wN2 = {wN,wN};
      #pragma unroll
      for(int p=0;p<4;p++){
        v2f sh = *(const v2f*)&shistT[k-1-i][s0 + 2*p];
        aR[p] = fma2(wR2, sh, aR[p]);
        aZ[p] = fma2(wZ2, sh, aZ[p]);
        aI[p] = fma2(wN2, sh, aI[p]);
      }
    }
    // main W.h: q ascending, c=0..3 -> dims ascending (identical chain to r10).
    // q < QLDS reads W from LDS; q >= QLDS streams from L2.
#define QBODY(WSRC)                                                            \
      {                                                                        \
        float4 wr4 = (WSRC)[q*G3 + rg];                                        \
        float4 wz4 = (WSRC)[q*G3 + 128 + rg];                                  \
        float4 wn4 = (WSRC)[q*G3 + 256 + rg];                                  \
        _Pragma("unroll")                                                      \
        for(int c=0;c<4;c++){                                                  \
          float wrc = (c==0)?wr4.x:(c==1)?wr4.y:(c==2)?wr4.z:wr4.w;            \
          float wzc = (c==0)?wz4.x:(c==1)?wz4.y:(c==2)?wz4.z:wz4.w;            \
          float wnc = (c==0)?wn4.x:(c==1)?wn4.y:(c==2)?wn4.z:wn4.w;            \
          v2f wr2 = {wrc,wrc}, wz2 = {wzc,wzc}, wn2 = {wnc,wnc};               \
          _Pragma("unroll")                                                    \
          for(int g=0;g<2;g++){                                                \
            float4 hv = hT4[4*q + c][g0 + g];                                  \
            v2f lo = {hv.x, hv.y}, hi = {hv.z, hv.w};                          \
            aR[2*g]   = fma2(wr2, lo, aR[2*g]);                                \
            aR[2*g+1] = fma2(wr2, hi, aR[2*g+1]);                              \
            aZ[2*g]   = fma2(wz2, lo, aZ[2*g]);                                \
            aZ[2*g+1] = fma2(wz2, hi, aZ[2*g+1]);                              \
            aH[2*g]   = fma2(wn2, lo, aH[2*g]);                                \
            aH[2*g+1] = fma2(wn2, hi, aH[2*g+1]);                              \
          }                                                                    \
        }                                                                      \
      }
    #pragma unroll 1
    for(int q=0;q<QLDS;q++) QBODY(wlds)
    #pragma unroll 1
    for(int q=QLDS;q<32;q++) QBODY(Wq4)
#undef QBODY
    __syncthreads();   // all hT4 (old h) reads complete
    // gates fused in-thread (identical per-cell formulas)
    #pragma unroll
    for(int s=0;s<8;s++){
      int p = s >> 1, e = s & 1;
      float aRv = aR[p][e], aZv = aZ[p][e], aIv = aI[p][e], aHv = aH[p][e];
      float rr = 1.0f/(1.0f+expf(-aRv));
      float zz = 1.0f/(1.0f+expf(-aZv));
      float nn = tanhf(aIv + rr*aHv);
      float hn = (1.0f-zz)*nn + zz*hold[s];
      hold[s] = hn;
      ((float*)&hT4[rg][g0 + (s>>2)])[s & 3] = hn;
    }
    __syncthreads();
    // projection: 96 threads (identical l-order); h[s][l] at word l*36+s
    if (t < SPB*3){
      int s = t/3, c2 = t%3;
      const float* hT = (const float*)hT4;
      float acc = bp[c2];
      for(int l=0;l<HID;l++) acc = fmaf(hT[l*36 + s], wp[l*3+c2], acc);
      parr[s][c2] = acc;
    }
    __syncthreads();
    // sampling: 32 threads (identical math/order)
    if (t < SPB){
      int s = t, gs = b*SPB + s;
      float p0 = parr[s][0], loc = parr[s][1], p2 = parr[s][2];
      float df = 2.0f + softplus_f(p0);
      float half_df = df*0.5f;
      float sigma = softplus_f(p2);
      uint32_t kn0 = skeys[k*4+0], kn1 = skeys[k*4+1];
      uint32_t kg0 = skeys[k*4+2], kg1 = skeys[k*4+3];
      uint32_t bnb = tf_bits_at(kn0, kn1, (uint32_t)gs);
      const float lo = -0.99999994f;
      float un = fmaxf(lo, bits_to_f01(bnb)*2.0f + lo);
      float nval = 1.41421356f * erfinv32(un);
      uint32_t gk0, gk1;
      threefry(kg0, kg1, 0u, (uint32_t)gs, gk0, gk1);
      float gmm = gamma_sample(gk0, gk1, half_df);
      float tval = nval * sqrtf(half_df / gmm);
      float samp = (loc + sigma*tval)*sc;
      out[gs*PRED + k] = samp;
      shistT[k][s] = samp / sc;
    }
    __syncthreads();
  }
}

extern "C" void kernel_launch(void* const* d_in, const int* in_sizes, int n_in,
                              void* d_out, int out_size, void* d_ws, size_t ws_size,
                              hipStream_t stream){
  const float* x     = (const float*)d_in[0];
  const float* xmark = (const float*)d_in[1];
  const float* ymark = (const float*)d_in[2];
  const float* Wemb  = (const float*)d_in[3];
  const float* bemb  = (const float*)d_in[4];
  const float* Wih   = (const float*)d_in[5];
  const float* Whh   = (const float*)d_in[6];
  const float* bih   = (const float*)d_in[7];
  const float* bhh   = (const float*)d_in[8];
  const float* Wproj = (const float*)d_in[9];
  const float* bproj = (const float*)d_in[10];
  float* ws  = (float*)d_ws;
  float* out = (float*)d_out;

  hipLaunchKernelGGL(k1_prep, dim3(1), dim3(256), 0, stream, x, xmark, ymark, Wemb, bemb, ws);
  hipLaunchKernelGGL(k2_gi, dim3(288), dim3(256), 0, stream, Wih, bih, bhh, ws);
  hipLaunchKernelGGL(k2b_wiht, dim3((PRED*G3+255)/256), dim3(256), 0, stream, Wih, ws);
  hipLaunchKernelGGL(k3_enc, dim3(1), dim3(384), 0, stream, Whh, bhh, ws);
  hipLaunchKernelGGL(k5_wq, dim3((32*G3+255)/256), dim3(256), 0, stream, Whh, ws);
  hipLaunchKernelGGL(k4_dec, dim3(NSAMP/SPB), dim3(THR4), 0, stream, Whh, bhh, Wproj, bproj, ws, out);
}

// Round 17
// 718.960 us; speedup vs baseline: 1.1245x; 1.0480x over previous
//
#include <hip/hip_runtime.h>
#include <stdint.h>

#define HIST 336
#define CNTX 168
#define PRED 24
#define HID 128
#define NFEAT 5
#define EMB 50
#define NLAGS 168
#define IN_DIM 218
#define NSAMP 8192
#define G3 384

// workspace layout (float offsets)
#define WS_XS     0
#define WS_SC     336
#define WS_TF     340
#define WS_YM     8740
#define WS_KEYS   9940
#define WS_ENCGI  10036
#define WS_WQ     10036
#define WS_GISH   74548
#define WS_HLAST  83764
#define WS_WIHT   83892

typedef float v2f __attribute__((ext_vector_type(2)));
__device__ __forceinline__ v2f fma2(v2f a, v2f b, v2f c){ return __builtin_elementwise_fma(a,b,c); }

// ---------------- threefry2x32 core (20 rounds) ----------------
__device__ __forceinline__ uint32_t rotl32(uint32_t v, int r){ return (v<<r)|(v>>(32-r)); }

__device__ __forceinline__ void threefry(uint32_t k0, uint32_t k1, uint32_t x0, uint32_t x1,
                                         uint32_t &o0, uint32_t &o1){
  uint32_t ks2 = k0 ^ k1 ^ 0x1BD11BDAu;
  x0 += k0; x1 += k1;
#define TFR(a) { x0 += x1; x1 = rotl32(x1,(a)); x1 ^= x0; }
  TFR(13) TFR(15) TFR(26) TFR(6)
  x0 += k1; x1 += ks2 + 1u;
  TFR(17) TFR(29) TFR(16) TFR(24)
  x0 += ks2; x1 += k0 + 2u;
  TFR(13) TFR(15) TFR(26) TFR(6)
  x0 += k0; x1 += k1 + 3u;
  TFR(17) TFR(29) TFR(16) TFR(24)
  x0 += k1; x1 += ks2 + 4u;
  TFR(13) TFR(15) TFR(26) TFR(6)
  x0 += ks2; x1 += k0 + 5u;
#undef TFR
  o0 = x0; o1 = x1;
}

// ---------------- partitionable (foldlike) JAX PRNG semantics ----------------
__device__ __forceinline__ void tf_split2(uint32_t k0, uint32_t k1,
                                          uint32_t &a0, uint32_t &a1,
                                          uint32_t &b0, uint32_t &b1){
  threefry(k0,k1, 0u,0u, a0,a1);
  threefry(k0,k1, 0u,1u, b0,b1);
}

__device__ __forceinline__ void tf_split3(uint32_t k0, uint32_t k1,
                                          uint32_t &a0, uint32_t &a1,
                                          uint32_t &b0, uint32_t &b1,
                                          uint32_t &c0, uint32_t &c1){
  threefry(k0,k1, 0u,0u, a0,a1);
  threefry(k0,k1, 0u,1u, b0,b1);
  threefry(k0,k1, 0u,2u, c0,c1);
}

__device__ __forceinline__ uint32_t tf_bits1(uint32_t k0, uint32_t k1){
  uint32_t o0,o1; threefry(k0,k1, 0u,0u, o0,o1); return o0 ^ o1;
}

__device__ __forceinline__ uint32_t tf_bits_at(uint32_t k0, uint32_t k1, uint32_t i){
  uint32_t o0,o1; threefry(k0,k1, 0u,i, o0,o1); return o0 ^ o1;
}

__device__ __forceinline__ float bits_to_f01(uint32_t b){
  return __uint_as_float((b>>9) | 0x3f800000u) - 1.0f;
}

// XLA ErfInv32 polynomial
__device__ __forceinline__ float erfinv32(float x){
  float w = -log1pf(-x*x);
  float p;
  if (w < 5.0f){
    w = w - 2.5f;
    p = 2.81022636e-08f;
    p = fmaf(p, w, 3.43273939e-07f);
    p = fmaf(p, w, -3.5233877e-06f);
    p = fmaf(p, w, -4.39150654e-06f);
    p = fmaf(p, w, 0.00021858087f);
    p = fmaf(p, w, -0.00125372503f);
    p = fmaf(p, w, -0.00417768164f);
    p = fmaf(p, w, 0.246640727f);
    p = fmaf(p, w, 1.50140941f);
  } else {
    w = sqrtf(w) - 3.0f;
    p = -0.000200214257f;
    p = fmaf(p, w, 0.000100950558f);
    p = fmaf(p, w, 0.00134934322f);
    p = fmaf(p, w, -0.00367342844f);
    p = fmaf(p, w, 0.00573950773f);
    p = fmaf(p, w, -0.0076224613f);
    p = fmaf(p, w, 0.00943887047f);
    p = fmaf(p, w, 1.00167406f);
    p = fmaf(p, w, 2.83297682f);
  }
  return p*x;
}

__device__ __forceinline__ float normal_from_key(uint32_t k0, uint32_t k1){
  uint32_t b = tf_bits1(k0,k1);
  const float lo = -0.99999994f;
  float f = bits_to_f01(b);
  float u = fmaxf(lo, f*2.0f + lo);
  return 1.41421356f * erfinv32(u);
}

// JAX _gamma_one, alpha >= 1 branch (boost==1)
__device__ float gamma_sample(uint32_t k0, uint32_t k1, float alpha){
  float d = __fsub_rn(alpha, 0.33333334f);
  float c = 0.33333334f / sqrtf(d);
  uint32_t ck0,ck1, sb0,sb1;
  tf_split2(k0,k1, ck0,ck1, sb0,sb1);
  float V;
  for(;;){
    uint32_t nk0,nk1, xk0,xk1, uk0,uk1;
    tf_split3(ck0,ck1, nk0,nk1, xk0,xk1, uk0,uk1);
    ck0=nk0; ck1=nk1;
    float x, v;
    do {
      uint32_t xa0,xa1, xb0,xb1;
      tf_split2(xk0,xk1, xa0,xa1, xb0,xb1);
      xk0=xa0; xk1=xa1;
      x = normal_from_key(xb0,xb1);
      v = __fadd_rn(1.0f, __fmul_rn(x, c));
    } while (v <= 0.0f);
    float X  = __fmul_rn(x, x);
    float Vv = __fmul_rn(__fmul_rn(v, v), v);
    float U  = bits_to_f01(tf_bits1(uk0,uk1));
    float t1 = __fsub_rn(1.0f, __fmul_rn(0.0331f, __fmul_rn(X, X)));
    bool cont = (U >= t1);
    if (cont){
      float lhs = logf(U);
      float rhs = __fadd_rn(__fmul_rn(0.5f, X),
                  __fmul_rn(d, __fadd_rn(__fsub_rn(1.0f, Vv), logf(Vv))));
      cont = (lhs >= rhs);
    }
    if (!cont){ V = Vv; break; }
  }
  return d*V;
}

__device__ __forceinline__ float softplus_f(float x){
  float amax = fmaxf(x, 0.0f);
  return amax + log1pf(expf(-fabsf(x)));
}

// ---------------- K1: scale, xs, tf, ym, step keys ----------------
__global__ __launch_bounds__(256) void k1_prep(const float* __restrict__ x,
                                               const float* __restrict__ xmark,
                                               const float* __restrict__ ymark,
                                               const float* __restrict__ Wemb,
                                               const float* __restrict__ bemb,
                                               float* __restrict__ ws){
  __shared__ float red[256];
  __shared__ float s_sc;
  int t = threadIdx.x;
  float a = 0.f;
  if (t < CNTX) a = fabsf(x[CNTX + t]);
  red[t] = a;
  __syncthreads();
  for(int s=128; s>0; s>>=1){ if(t<s) red[t]+=red[t+s]; __syncthreads(); }
  if (t==0){ s_sc = fmaxf(red[0]/168.0f, 1e-5f); ws[WS_SC]=s_sc; }
  __syncthreads();
  float sc = s_sc;
  for(int i=t; i<HIST; i+=256) ws[WS_XS+i] = x[i]/sc;
  for(int idx=t; idx<CNTX*EMB; idx+=256){
    int tt = idx/EMB, e = idx%EMB;
    float acc = bemb[e];
    for(int f=0; f<NFEAT; f++) acc += xmark[(CNTX+tt)*NFEAT+f]*Wemb[f*EMB+e];
    ws[WS_TF+idx] = acc;
  }
  for(int idx=t; idx<PRED*EMB; idx+=256){
    int kk = idx/EMB, e = idx%EMB;
    float acc = bemb[e];
    for(int f=0; f<NFEAT; f++) acc += ymark[kk*NFEAT+f]*Wemb[f*EMB+e];
    ws[WS_YM+idx] = acc;
  }
  if (t==0){
    uint32_t* kp = reinterpret_cast<uint32_t*>(ws + WS_KEYS);
    uint32_t c0 = 0u, c1 = 42u;
    for(int k=0;k<PRED;k++){
      uint32_t a0,a1,b0,b1;
      tf_split2(c0,c1, a0,a1, b0,b1);
      c0=a0; c1=a1;
      uint32_t n0,n1,g0,g1;
      tf_split2(b0,b1, n0,n1, g0,g1);
      kp[k*4+0]=n0; kp[k*4+1]=n1; kp[k*4+2]=g0; kp[k*4+3]=g1;
    }
  }
}

// ---------------- K2: enc_gi (t<168) and gi_shared (t>=168) ----------------
__global__ __launch_bounds__(256) void k2_gi(const float* __restrict__ Wih,
                                             const float* __restrict__ bih,
                                             const float* __restrict__ bhh,
                                             float* __restrict__ ws){
  int idx = blockIdx.x*256 + threadIdx.x;
  if (idx >= 192*G3) return;
  int t = idx / G3, r = idx % G3;
  const float* wr = Wih + r*IN_DIM;
  const float* xs = ws + WS_XS;
  float acc = bih[r] + (r < 256 ? bhh[r] : 0.0f);
  if (t < CNTX){
    const float* tf = ws + WS_TF + t*EMB;
    for(int j=0;j<NLAGS;j++) acc += wr[j]*xs[CNTX + t - 1 - j];
    for(int e=0;e<EMB;e++)   acc += wr[NLAGS+e]*tf[e];
    ws[WS_ENCGI + t*G3 + r] = acc;
  } else {
    int k = t - CNTX;
    const float* ym = ws + WS_YM + k*EMB;
    for(int e=0;e<EMB;e++)   acc += wr[NLAGS+e]*ym[e];
    for(int i=k;i<NLAGS;i++) acc += wr[i]*xs[HIST-1-i+k];
    ws[WS_GISH + k*G3 + r] = acc;
  }
}

// ---------------- K2b: transpose W_ih lag cols 0..23 ----------------
__global__ __launch_bounds__(256) void k2b_wiht(const float* __restrict__ Wih,
                                                float* __restrict__ ws){
  int idx = blockIdx.x*256 + threadIdx.x;
  if (idx >= PRED*G3) return;
  int r = idx / PRED, i = idx % PRED;
  ws[WS_WIHT + i*G3 + r] = Wih[r*IN_DIM + i];
}

// ---------------- K3: encoder GRU (unchanged from passing r5/r6) ----------------
__global__ __launch_bounds__(384) void k3_enc(const float* __restrict__ Whh,
                                              const float* __restrict__ bhh,
                                              float* __restrict__ ws){
  __shared__ __align__(16) float h[HID];
  __shared__ float grz[256];
  __shared__ float hnv[HID];
  int r = threadIdx.x;
  float4 w[32];
  const float4* wr = (const float4*)(Whh + r*HID);
  #pragma unroll
  for(int i=0;i<32;i++) w[i] = wr[i];
  float bh = (r>=256)? bhh[r] : 0.0f;
  if (r < HID) h[r] = 0.0f;
  __syncthreads();
  const float* encgi = ws + WS_ENCGI;
  for(int t=0;t<CNTX;t++){
    float acc = 0.f;
    #pragma unroll
    for(int i=0;i<32;i++){
      float4 hv = *(const float4*)&h[4*i];
      float4 ww = w[i];
      acc = fmaf(ww.x,hv.x, fmaf(ww.y,hv.y, fmaf(ww.z,hv.z, fmaf(ww.w,hv.w, acc))));
    }
    if (r < 256) grz[r] = encgi[t*G3+r] + acc;
    else         hnv[r-256] = acc + bh;
    __syncthreads();
    if (r < HID){
      float rr = 1.0f/(1.0f+expf(-grz[r]));
      float zz = 1.0f/(1.0f+expf(-grz[128+r]));
      float inv = encgi[t*G3+256+r];
      float nn = tanhf(inv + rr*hnv[r]);
      h[r] = (1.0f-zz)*nn + zz*h[r];
    }
    __syncthreads();
  }
  if (r < HID) ws[WS_HLAST + r] = h[r];
}

// ---------------- K5: build Wq[q][r] = float4 W[r][4q..4q+3] (into dead ENCGI area) ----------------
__global__ __launch_bounds__(256) void k5_wq(const float* __restrict__ Whh,
                                             float* __restrict__ ws){
  int idx = blockIdx.x*256 + threadIdx.x;
  if (idx >= 32*G3) return;
  int q = idx / G3, r = idx % G3;
  float4 v = *(const float4*)&Whh[r*HID + q*4];
  ((float4*)(ws + WS_WQ))[idx] = v;
}

// ---------------- K4: decoder — W streamed from L2, hT4 broadcast, fused gates ----
// 256 blocks x 512 threads. Thread (rg=t&127, sg=t>>7) owns rows {rg,128+rg,256+rg} and
// samples s0=8*sg..+7. All four gate pre-activations computed in-thread; gates fused.
// Accumulation chains identical to passing r5..r15: init gish/bhh -> lags i-ascending ->
// W.h with dims 4q+c ascending 0..127.
#define SPB 32
#define THR4 512

__global__ __launch_bounds__(512) void k4_dec(const float* __restrict__ Whh,
                                              const float* __restrict__ bhh,
                                              const float* __restrict__ Wproj,
                                              const float* __restrict__ bproj,
                                              const float* __restrict__ ws,
                                              float* __restrict__ out){
  __shared__ __align__(16) float4 hT4[128][9];   // 18.4 KB: [dim][group] = h of samples 4g..4g+3
  __shared__ float wihT_l[24*G3];                // 36.9 KB lag weights
  __shared__ float shistT[25][34];               // 3.4 KB [k][s]
  __shared__ float parr[SPB][4];
  __shared__ float wp[HID*3];
  __shared__ float bp[3];
  __shared__ uint32_t skeys[PRED*4];

  int t = threadIdx.x;
  int b = blockIdx.x;
  int rg = t & 127;
  int sg = t >> 7;
  int s0 = sg*8;
  int g0 = sg*2;       // hT4 group base (2 groups of 4 samples)

  float bhn = bhh[256 + rg];

  for(int idx=t; idx<24*G3; idx+=THR4) wihT_l[idx] = ws[WS_WIHT + idx];
  for(int idx=t; idx<HID*3; idx+=THR4) wp[idx] = Wproj[idx];
  if (t < 3) bp[t] = bproj[t];
  if (t < PRED*4) skeys[t] = reinterpret_cast<const uint32_t*>(ws + WS_KEYS)[t];
  if (t < 128){
    float hl = ws[WS_HLAST + t];
    float4 v = {hl,hl,hl,hl};
    #pragma unroll
    for(int g=0;g<8;g++) hT4[t][g] = v;
  }
  float hold[8];
  {
    float hl = ws[WS_HLAST + rg];
    #pragma unroll
    for(int s=0;s<8;s++) hold[s] = hl;
  }
  float sc = ws[WS_SC];
  const float* gish = ws + WS_GISH;
  const float4* Wq4 = (const float4*)(ws + WS_WQ);
  __syncthreads();

  #pragma unroll 1
  for(int k=0;k<PRED;k++){
    // pair accumulators: p -> samples (s0+2p, s0+2p+1)
    v2f aR[4], aZ[4], aH[4], aI[4];
    {
      float gR = gish[k*G3 + rg];
      float gZ = gish[k*G3 + 128 + rg];
      float gI = gish[k*G3 + 256 + rg];
      #pragma unroll
      for(int p=0;p<4;p++){
        aR[p] = (v2f){gR,gR}; aZ[p] = (v2f){gZ,gZ};
        aI[p] = (v2f){gI,gI}; aH[p] = (v2f){bhn,bhn};
      }
    }
    // lag chains (i ascending — identical order)
    #pragma unroll 1
    for(int i=0;i<k;i++){
      float wR = wihT_l[i*G3 + rg];
      float wZ = wihT_l[i*G3 + 128 + rg];
      float wN = wihT_l[i*G3 + 256 + rg];
      v2f wR2 = {wR,wR}, wZ2 = {wZ,wZ}, wN2 = {wN,wN};
      #pragma unroll
      for(int p=0;p<4;p++){
        v2f sh = *(const v2f*)&shistT[k-1-i][s0 + 2*p];
        aR[p] = fma2(wR2, sh, aR[p]);
        aZ[p] = fma2(wZ2, sh, aZ[p]);
        aI[p] = fma2(wN2, sh, aI[p]);
      }
    }
    // main W.h: q ascending, c=0..3 -> k dims ascending (identical chain)
    #pragma unroll 1
    for(int q=0;q<32;q++){
      float4 wr4 = Wq4[q*G3 + rg];
      float4 wz4 = Wq4[q*G3 + 128 + rg];
      float4 wn4 = Wq4[q*G3 + 256 + rg];
      #pragma unroll
      for(int c=0;c<4;c++){
        float wrc = (c==0)?wr4.x:(c==1)?wr4.y:(c==2)?wr4.z:wr4.w;
        float wzc = (c==0)?wz4.x:(c==1)?wz4.y:(c==2)?wz4.z:wz4.w;
        float wnc = (c==0)?wn4.x:(c==1)?wn4.y:(c==2)?wn4.z:wn4.w;
        v2f wr2 = {wrc,wrc}, wz2 = {wzc,wzc}, wn2 = {wnc,wnc};
        #pragma unroll
        for(int g=0;g<2;g++){
          float4 hv = hT4[4*q + c][g0 + g];
          v2f lo = {hv.x, hv.y}, hi = {hv.z, hv.w};
          aR[2*g]   = fma2(wr2, lo, aR[2*g]);
          aR[2*g+1] = fma2(wr2, hi, aR[2*g+1]);
          aZ[2*g]   = fma2(wz2, lo, aZ[2*g]);
          aZ[2*g+1] = fma2(wz2, hi, aZ[2*g+1]);
          aH[2*g]   = fma2(wn2, lo, aH[2*g]);
          aH[2*g+1] = fma2(wn2, hi, aH[2*g+1]);
        }
      }
    }
    __syncthreads();   // all hT4 (old h) reads complete
    // gates fused in-thread (identical per-cell formulas; hold = own previous h)
    #pragma unroll
    for(int s=0;s<8;s++){
      int p = s >> 1, e = s & 1;
      float aRv = aR[p][e], aZv = aZ[p][e], aIv = aI[p][e], aHv = aH[p][e];
      float rr = 1.0f/(1.0f+expf(-aRv));
      float zz = 1.0f/(1.0f+expf(-aZv));
      float nn = tanhf(aIv + rr*aHv);
      float hn = (1.0f-zz)*nn + zz*hold[s];
      hold[s] = hn;
      ((float*)&hT4[rg][g0 + (s>>2)])[s & 3] = hn;
    }
    __syncthreads();
    // projection: 96 threads (identical l-order); h[s][l] at word l*36+s
    if (t < SPB*3){
      int s = t/3, c2 = t%3;
      const float* hT = (const float*)hT4;
      float acc = bp[c2];
      for(int l=0;l<HID;l++) acc = fmaf(hT[l*36 + s], wp[l*3+c2], acc);
      parr[s][c2] = acc;
    }
    __syncthreads();
    // sampling: 32 threads (identical math/order)
    if (t < SPB){
      int s = t, gs = b*SPB + s;
      float p0 = parr[s][0], loc = parr[s][1], p2 = parr[s][2];
      float df = 2.0f + softplus_f(p0);
      float half_df = df*0.5f;
      float sigma = softplus_f(p2);
      uint32_t kn0 = skeys[k*4+0], kn1 = skeys[k*4+1];
      uint32_t kg0 = skeys[k*4+2], kg1 = skeys[k*4+3];
      uint32_t bnb = tf_bits_at(kn0, kn1, (uint32_t)gs);
      const float lo = -0.99999994f;
      float un = fmaxf(lo, bits_to_f01(bnb)*2.0f + lo);
      float nval = 1.41421356f * erfinv32(un);
      uint32_t gk0, gk1;
      threefry(kg0, kg1, 0u, (uint32_t)gs, gk0, gk1);
      float gmm = gamma_sample(gk0, gk1, half_df);
      float tval = nval * sqrtf(half_df / gmm);
      float samp = (loc + sigma*tval)*sc;
      out[gs*PRED + k] = samp;
      shistT[k][s] = samp / sc;
    }
    __syncthreads();
  }
}

extern "C" void kernel_launch(void* const* d_in, const int* in_sizes, int n_in,
                              void* d_out, int out_size, void* d_ws, size_t ws_size,
                              hipStream_t stream){
  const float* x     = (const float*)d_in[0];
  const float* xmark = (const float*)d_in[1];
  const float* ymark = (const float*)d_in[2];
  const float* Wemb  = (const float*)d_in[3];
  const float* bemb  = (const float*)d_in[4];
  const float* Wih   = (const float*)d_in[5];
  const float* Whh   = (const float*)d_in[6];
  const float* bih   = (const float*)d_in[7];
  const float* bhh   = (const float*)d_in[8];
  const float* Wproj = (const float*)d_in[9];
  const float* bproj = (const float*)d_in[10];
  float* ws  = (float*)d_ws;
  float* out = (float*)d_out;

  hipLaunchKernelGGL(k1_prep, dim3(1), dim3(256), 0, stream, x, xmark, ymark, Wemb, bemb, ws);
  hipLaunchKernelGGL(k2_gi, dim3(288), dim3(256), 0, stream, Wih, bih, bhh, ws);
  hipLaunchKernelGGL(k2b_wiht, dim3((PRED*G3+255)/256), dim3(256), 0, stream, Wih, ws);
  hipLaunchKernelGGL(k3_enc, dim3(1), dim3(384), 0, stream, Whh, bhh, ws);
  hipLaunchKernelGGL(k5_wq, dim3((32*G3+255)/256), dim3(256), 0, stream, Whh, ws);
  hipLaunchKernelGGL(k4_dec, dim3(NSAMP/SPB), dim3(THR4), 0, stream, Whh, bhh, Wproj, bproj, ws, out);
}

// Round 18
// 712.662 us; speedup vs baseline: 1.1344x; 1.0088x over previous
//
#include <hip/hip_runtime.h>
#include <stdint.h>

#define HIST 336
#define CNTX 168
#define PRED 24
#define HID 128
#define NFEAT 5
#define EMB 50
#define NLAGS 168
#define IN_DIM 218
#define NSAMP 8192
#define G3 384

// workspace layout (float offsets)
#define WS_XS     0
#define WS_SC     336
#define WS_TF     340
#define WS_YM     8740
#define WS_KEYS   9940
#define WS_ENCGI  10036
#define WS_WQ     10036
#define WS_GISH   74548
#define WS_HLAST  83764
#define WS_WIHT   83892

typedef float v2f __attribute__((ext_vector_type(2)));
__device__ __forceinline__ v2f fma2(v2f a, v2f b, v2f c){ return __builtin_elementwise_fma(a,b,c); }

// ---------------- threefry2x32 core (20 rounds) ----------------
__device__ __forceinline__ uint32_t rotl32(uint32_t v, int r){ return (v<<r)|(v>>(32-r)); }

__device__ __forceinline__ void threefry(uint32_t k0, uint32_t k1, uint32_t x0, uint32_t x1,
                                         uint32_t &o0, uint32_t &o1){
  uint32_t ks2 = k0 ^ k1 ^ 0x1BD11BDAu;
  x0 += k0; x1 += k1;
#define TFR(a) { x0 += x1; x1 = rotl32(x1,(a)); x1 ^= x0; }
  TFR(13) TFR(15) TFR(26) TFR(6)
  x0 += k1; x1 += ks2 + 1u;
  TFR(17) TFR(29) TFR(16) TFR(24)
  x0 += ks2; x1 += k0 + 2u;
  TFR(13) TFR(15) TFR(26) TFR(6)
  x0 += k0; x1 += k1 + 3u;
  TFR(17) TFR(29) TFR(16) TFR(24)
  x0 += k1; x1 += ks2 + 4u;
  TFR(13) TFR(15) TFR(26) TFR(6)
  x0 += ks2; x1 += k0 + 5u;
#undef TFR
  o0 = x0; o1 = x1;
}

// ---------------- partitionable (foldlike) JAX PRNG semantics ----------------
__device__ __forceinline__ void tf_split2(uint32_t k0, uint32_t k1,
                                          uint32_t &a0, uint32_t &a1,
                                          uint32_t &b0, uint32_t &b1){
  threefry(k0,k1, 0u,0u, a0,a1);
  threefry(k0,k1, 0u,1u, b0,b1);
}

__device__ __forceinline__ void tf_split3(uint32_t k0, uint32_t k1,
                                          uint32_t &a0, uint32_t &a1,
                                          uint32_t &b0, uint32_t &b1,
                                          uint32_t &c0, uint32_t &c1){
  threefry(k0,k1, 0u,0u, a0,a1);
  threefry(k0,k1, 0u,1u, b0,b1);
  threefry(k0,k1, 0u,2u, c0,c1);
}

__device__ __forceinline__ uint32_t tf_bits1(uint32_t k0, uint32_t k1){
  uint32_t o0,o1; threefry(k0,k1, 0u,0u, o0,o1); return o0 ^ o1;
}

__device__ __forceinline__ uint32_t tf_bits_at(uint32_t k0, uint32_t k1, uint32_t i){
  uint32_t o0,o1; threefry(k0,k1, 0u,i, o0,o1); return o0 ^ o1;
}

__device__ __forceinline__ float bits_to_f01(uint32_t b){
  return __uint_as_float((b>>9) | 0x3f800000u) - 1.0f;
}

// XLA ErfInv32 polynomial
__device__ __forceinline__ float erfinv32(float x){
  float w = -log1pf(-x*x);
  float p;
  if (w < 5.0f){
    w = w - 2.5f;
    p = 2.81022636e-08f;
    p = fmaf(p, w, 3.43273939e-07f);
    p = fmaf(p, w, -3.5233877e-06f);
    p = fmaf(p, w, -4.39150654e-06f);
    p = fmaf(p, w, 0.00021858087f);
    p = fmaf(p, w, -0.00125372503f);
    p = fmaf(p, w, -0.00417768164f);
    p = fmaf(p, w, 0.246640727f);
    p = fmaf(p, w, 1.50140941f);
  } else {
    w = sqrtf(w) - 3.0f;
    p = -0.000200214257f;
    p = fmaf(p, w, 0.000100950558f);
    p = fmaf(p, w, 0.00134934322f);
    p = fmaf(p, w, -0.00367342844f);
    p = fmaf(p, w, 0.00573950773f);
    p = fmaf(p, w, -0.0076224613f);
    p = fmaf(p, w, 0.00943887047f);
    p = fmaf(p, w, 1.00167406f);
    p = fmaf(p, w, 2.83297682f);
  }
  return p*x;
}

__device__ __forceinline__ float normal_from_key(uint32_t k0, uint32_t k1){
  uint32_t b = tf_bits1(k0,k1);
  const float lo = -0.99999994f;
  float f = bits_to_f01(b);
  float u = fmaxf(lo, f*2.0f + lo);
  return 1.41421356f * erfinv32(u);
}

// JAX _gamma_one, alpha >= 1 branch (boost==1)
__device__ float gamma_sample(uint32_t k0, uint32_t k1, float alpha){
  float d = __fsub_rn(alpha, 0.33333334f);
  float c = 0.33333334f / sqrtf(d);
  uint32_t ck0,ck1, sb0,sb1;
  tf_split2(k0,k1, ck0,ck1, sb0,sb1);
  float V;
  for(;;){
    uint32_t nk0,nk1, xk0,xk1, uk0,uk1;
    tf_split3(ck0,ck1, nk0,nk1, xk0,xk1, uk0,uk1);
    ck0=nk0; ck1=nk1;
    float x, v;
    do {
      uint32_t xa0,xa1, xb0,xb1;
      tf_split2(xk0,xk1, xa0,xa1, xb0,xb1);
      xk0=xa0; xk1=xa1;
      x = normal_from_key(xb0,xb1);
      v = __fadd_rn(1.0f, __fmul_rn(x, c));
    } while (v <= 0.0f);
    float X  = __fmul_rn(x, x);
    float Vv = __fmul_rn(__fmul_rn(v, v), v);
    float U  = bits_to_f01(tf_bits1(uk0,uk1));
    float t1 = __fsub_rn(1.0f, __fmul_rn(0.0331f, __fmul_rn(X, X)));
    bool cont = (U >= t1);
    if (cont){
      float lhs = logf(U);
      float rhs = __fadd_rn(__fmul_rn(0.5f, X),
                  __fmul_rn(d, __fadd_rn(__fsub_rn(1.0f, Vv), logf(Vv))));
      cont = (lhs >= rhs);
    }
    if (!cont){ V = Vv; break; }
  }
  return d*V;
}

__device__ __forceinline__ float softplus_f(float x){
  float amax = fmaxf(x, 0.0f);
  return amax + log1pf(expf(-fabsf(x)));
}

// ---------------- K1: scale, xs, tf, ym, step keys ----------------
__global__ __launch_bounds__(256) void k1_prep(const float* __restrict__ x,
                                               const float* __restrict__ xmark,
                                               const float* __restrict__ ymark,
                                               const float* __restrict__ Wemb,
                                               const float* __restrict__ bemb,
                                               float* __restrict__ ws){
  __shared__ float red[256];
  __shared__ float s_sc;
  int t = threadIdx.x;
  float a = 0.f;
  if (t < CNTX) a = fabsf(x[CNTX + t]);
  red[t] = a;
  __syncthreads();
  for(int s=128; s>0; s>>=1){ if(t<s) red[t]+=red[t+s]; __syncthreads(); }
  if (t==0){ s_sc = fmaxf(red[0]/168.0f, 1e-5f); ws[WS_SC]=s_sc; }
  __syncthreads();
  float sc = s_sc;
  for(int i=t; i<HIST; i+=256) ws[WS_XS+i] = x[i]/sc;
  for(int idx=t; idx<CNTX*EMB; idx+=256){
    int tt = idx/EMB, e = idx%EMB;
    float acc = bemb[e];
    for(int f=0; f<NFEAT; f++) acc += xmark[(CNTX+tt)*NFEAT+f]*Wemb[f*EMB+e];
    ws[WS_TF+idx] = acc;
  }
  for(int idx=t; idx<PRED*EMB; idx+=256){
    int kk = idx/EMB, e = idx%EMB;
    float acc = bemb[e];
    for(int f=0; f<NFEAT; f++) acc += ymark[kk*NFEAT+f]*Wemb[f*EMB+e];
    ws[WS_YM+idx] = acc;
  }
  if (t==0){
    uint32_t* kp = reinterpret_cast<uint32_t*>(ws + WS_KEYS);
    uint32_t c0 = 0u, c1 = 42u;
    for(int k=0;k<PRED;k++){
      uint32_t a0,a1,b0,b1;
      tf_split2(c0,c1, a0,a1, b0,b1);
      c0=a0; c1=a1;
      uint32_t n0,n1,g0,g1;
      tf_split2(b0,b1, n0,n1, g0,g1);
      kp[k*4+0]=n0; kp[k*4+1]=n1; kp[k*4+2]=g0; kp[k*4+3]=g1;
    }
  }
}

// ---------------- K2: enc_gi / gi_shared with broadcast W rows + fused wihT transpose ----
// Index remap: thread handles (r = idx/192, t = idx%192) so W-row reads are wave-uniform
// (broadcast) and xs reads are lane-consecutive. Per-output arithmetic identical to r5..r17.
// Tail range (idx >= 384*192) does the k2b transpose of W_ih lag cols 0..23.
__global__ __launch_bounds__(256) void k2_gi(const float* __restrict__ Wih,
                                             const float* __restrict__ bih,
                                             const float* __restrict__ bhh,
                                             float* __restrict__ ws){
  int idx = blockIdx.x*256 + threadIdx.x;
  if (idx < G3*192){
    int r = idx / 192, t = idx % 192;
    const float* wr = Wih + r*IN_DIM;
    const float* xs = ws + WS_XS;
    float acc = bih[r] + (r < 256 ? bhh[r] : 0.0f);
    if (t < CNTX){
      const float* tf = ws + WS_TF + t*EMB;
      for(int j=0;j<NLAGS;j++) acc += wr[j]*xs[CNTX + t - 1 - j];
      for(int e=0;e<EMB;e++)   acc += wr[NLAGS+e]*tf[e];
      ws[WS_ENCGI + t*G3 + r] = acc;
    } else {
      int k = t - CNTX;
      const float* ym = ws + WS_YM + k*EMB;
      for(int e=0;e<EMB;e++)   acc += wr[NLAGS+e]*ym[e];
      for(int i=k;i<NLAGS;i++) acc += wr[i]*xs[HIST-1-i+k];
      ws[WS_GISH + k*G3 + r] = acc;
    }
  } else {
    int j = idx - G3*192;
    if (j < PRED*G3){
      int r = j / PRED, i = j % PRED;
      ws[WS_WIHT + i*G3 + r] = Wih[r*IN_DIM + i];
    }
  }
}

// ---------------- K3: encoder GRU + fused Wq build (ENCGI dead after the loop) ----------
__global__ __launch_bounds__(384) void k3_enc(const float* __restrict__ Whh,
                                              const float* __restrict__ bhh,
                                              float* __restrict__ ws){
  __shared__ __align__(16) float h[HID];
  __shared__ float grz[256];
  __shared__ float hnv[HID];
  int r = threadIdx.x;
  float4 w[32];
  const float4* wr = (const float4*)(Whh + r*HID);
  #pragma unroll
  for(int i=0;i<32;i++) w[i] = wr[i];
  float bh = (r>=256)? bhh[r] : 0.0f;
  if (r < HID) h[r] = 0.0f;
  __syncthreads();
  const float* encgi = ws + WS_ENCGI;
  for(int t=0;t<CNTX;t++){
    float acc = 0.f;
    #pragma unroll
    for(int i=0;i<32;i++){
      float4 hv = *(const float4*)&h[4*i];
      float4 ww = w[i];
      acc = fmaf(ww.x,hv.x, fmaf(ww.y,hv.y, fmaf(ww.z,hv.z, fmaf(ww.w,hv.w, acc))));
    }
    if (r < 256) grz[r] = encgi[t*G3+r] + acc;
    else         hnv[r-256] = acc + bh;
    __syncthreads();
    if (r < HID){
      float rr = 1.0f/(1.0f+expf(-grz[r]));
      float zz = 1.0f/(1.0f+expf(-grz[128+r]));
      float inv = encgi[t*G3+256+r];
      float nn = tanhf(inv + rr*hnv[r]);
      h[r] = (1.0f-zz)*nn + zz*h[r];
    }
    __syncthreads();
  }
  if (r < HID) ws[WS_HLAST + r] = h[r];
  // fused K5: all steps done (last loop iteration ended with a barrier), ENCGI now dead.
  // Build Wq[q][rr] = float4 W[rr][4q..4q+3] into the ENCGI region.
  float4* wq = (float4*)(ws + WS_WQ);
  for(int idx=r; idx<32*G3; idx+=384){
    int q = idx / G3, rr = idx % G3;
    wq[idx] = *(const float4*)&Whh[rr*HID + q*4];
  }
}

// ---------------- K4: decoder — W streamed from L2, hT4 broadcast, fused gates ----
// (verbatim r10/r17 structure — proven 478 us, stable)
#define SPB 32
#define THR4 512

__global__ __launch_bounds__(512) void k4_dec(const float* __restrict__ Whh,
                                              const float* __restrict__ bhh,
                                              const float* __restrict__ Wproj,
                                              const float* __restrict__ bproj,
                                              const float* __restrict__ ws,
                                              float* __restrict__ out){
  __shared__ __align__(16) float4 hT4[128][9];   // 18.4 KB
  __shared__ float wihT_l[24*G3];                // 36.9 KB
  __shared__ float shistT[25][34];               // 3.4 KB
  __shared__ float parr[SPB][4];
  __shared__ float wp[HID*3];
  __shared__ float bp[3];
  __shared__ uint32_t skeys[PRED*4];

  int t = threadIdx.x;
  int b = blockIdx.x;
  int rg = t & 127;
  int sg = t >> 7;
  int s0 = sg*8;
  int g0 = sg*2;

  float bhn = bhh[256 + rg];

  for(int idx=t; idx<24*G3; idx+=THR4) wihT_l[idx] = ws[WS_WIHT + idx];
  for(int idx=t; idx<HID*3; idx+=THR4) wp[idx] = Wproj[idx];
  if (t < 3) bp[t] = bproj[t];
  if (t < PRED*4) skeys[t] = reinterpret_cast<const uint32_t*>(ws + WS_KEYS)[t];
  if (t < 128){
    float hl = ws[WS_HLAST + t];
    float4 v = {hl,hl,hl,hl};
    #pragma unroll
    for(int g=0;g<8;g++) hT4[t][g] = v;
  }
  float hold[8];
  {
    float hl = ws[WS_HLAST + rg];
    #pragma unroll
    for(int s=0;s<8;s++) hold[s] = hl;
  }
  float sc = ws[WS_SC];
  const float* gish = ws + WS_GISH;
  const float4* Wq4 = (const float4*)(ws + WS_WQ);
  __syncthreads();

  #pragma unroll 1
  for(int k=0;k<PRED;k++){
    v2f aR[4], aZ[4], aH[4], aI[4];
    {
      float gR = gish[k*G3 + rg];
      float gZ = gish[k*G3 + 128 + rg];
      float gI = gish[k*G3 + 256 + rg];
      #pragma unroll
      for(int p=0;p<4;p++){
        aR[p] = (v2f){gR,gR}; aZ[p] = (v2f){gZ,gZ};
        aI[p] = (v2f){gI,gI}; aH[p] = (v2f){bhn,bhn};
      }
    }
    // lag chains (i ascending — identical order)
    #pragma unroll 1
    for(int i=0;i<k;i++){
      float wR = wihT_l[i*G3 + rg];
      float wZ = wihT_l[i*G3 + 128 + rg];
      float wN = wihT_l[i*G3 + 256 + rg];
      v2f wR2 = {wR,wR}, wZ2 = {wZ,wZ}, wN2 = {wN,wN};
      #pragma unroll
      for(int p=0;p<4;p++){
        v2f sh = *(const v2f*)&shistT[k-1-i][s0 + 2*p];
        aR[p] = fma2(wR2, sh, aR[p]);
        aZ[p] = fma2(wZ2, sh, aZ[p]);
        aI[p] = fma2(wN2, sh, aI[p]);
      }
    }
    // main W.h: q ascending, c=0..3 -> k dims ascending (identical chain)
    #pragma unroll 1
    for(int q=0;q<32;q++){
      float4 wr4 = Wq4[q*G3 + rg];
      float4 wz4 = Wq4[q*G3 + 128 + rg];
      float4 wn4 = Wq4[q*G3 + 256 + rg];
      #pragma unroll
      for(int c=0;c<4;c++){
        float wrc = (c==0)?wr4.x:(c==1)?wr4.y:(c==2)?wr4.z:wr4.w;
        float wzc = (c==0)?wz4.x:(c==1)?wz4.y:(c==2)?wz4.z:wz4.w;
        float wnc = (c==0)?wn4.x:(c==1)?wn4.y:(c==2)?wn4.z:wn4.w;
        v2f wr2 = {wrc,wrc}, wz2 = {wzc,wzc}, wn2 = {wnc,wnc};
        #pragma unroll
        for(int g=0;g<2;g++){
          float4 hv = hT4[4*q + c][g0 + g];
          v2f lo = {hv.x, hv.y}, hi = {hv.z, hv.w};
          aR[2*g]   = fma2(wr2, lo, aR[2*g]);
          aR[2*g+1] = fma2(wr2, hi, aR[2*g+1]);
          aZ[2*g]   = fma2(wz2, lo, aZ[2*g]);
          aZ[2*g+1] = fma2(wz2, hi, aZ[2*g+1]);
          aH[2*g]   = fma2(wn2, lo, aH[2*g]);
          aH[2*g+1] = fma2(wn2, hi, aH[2*g+1]);
        }
      }
    }
    __syncthreads();   // all hT4 (old h) reads complete
    // gates fused in-thread (identical per-cell formulas; hold = own previous h)
    #pragma unroll
    for(int s=0;s<8;s++){
      int p = s >> 1, e = s & 1;
      float aRv = aR[p][e], aZv = aZ[p][e], aIv = aI[p][e], aHv = aH[p][e];
      float rr = 1.0f/(1.0f+expf(-aRv));
      float zz = 1.0f/(1.0f+expf(-aZv));
      float nn = tanhf(aIv + rr*aHv);
      float hn = (1.0f-zz)*nn + zz*hold[s];
      hold[s] = hn;
      ((float*)&hT4[rg][g0 + (s>>2)])[s & 3] = hn;
    }
    __syncthreads();
    // projection: 96 threads (identical l-order); h[s][l] at word l*36+s
    if (t < SPB*3){
      int s = t/3, c2 = t%3;
      const float* hT = (const float*)hT4;
      float acc = bp[c2];
      for(int l=0;l<HID;l++) acc = fmaf(hT[l*36 + s], wp[l*3+c2], acc);
      parr[s][c2] = acc;
    }
    __syncthreads();
    // sampling: 32 threads (identical math/order)
    if (t < SPB){
      int s = t, gs = b*SPB + s;
      float p0 = parr[s][0], loc = parr[s][1], p2 = parr[s][2];
      float df = 2.0f + softplus_f(p0);
      float half_df = df*0.5f;
      float sigma = softplus_f(p2);
      uint32_t kn0 = skeys[k*4+0], kn1 = skeys[k*4+1];
      uint32_t kg0 = skeys[k*4+2], kg1 = skeys[k*4+3];
      uint32_t bnb = tf_bits_at(kn0, kn1, (uint32_t)gs);
      const float lo = -0.99999994f;
      float un = fmaxf(lo, bits_to_f01(bnb)*2.0f + lo);
      float nval = 1.41421356f * erfinv32(un);
      uint32_t gk0, gk1;
      threefry(kg0, kg1, 0u, (uint32_t)gs, gk0, gk1);
      float gmm = gamma_sample(gk0, gk1, half_df);
      float tval = nval * sqrtf(half_df / gmm);
      float samp = (loc + sigma*tval)*sc;
      out[gs*PRED + k] = samp;
      shistT[k][s] = samp / sc;
    }
    __syncthreads();
  }
}

extern "C" void kernel_launch(void* const* d_in, const int* in_sizes, int n_in,
                              void* d_out, int out_size, void* d_ws, size_t ws_size,
                              hipStream_t stream){
  const float* x     = (const float*)d_in[0];
  const float* xmark = (const float*)d_in[1];
  const float* ymark = (const float*)d_in[2];
  const float* Wemb  = (const float*)d_in[3];
  const float* bemb  = (const float*)d_in[4];
  const float* Wih   = (const float*)d_in[5];
  const float* Whh   = (const float*)d_in[6];
  const float* bih   = (const float*)d_in[7];
  const float* bhh   = (const float*)d_in[8];
  const float* Wproj = (const float*)d_in[9];
  const float* bproj = (const float*)d_in[10];
  float* ws  = (float*)d_ws;
  float* out = (float*)d_out;

  // k2 grid: 384*192 matvec threads + 24*384 transpose threads = 82944 -> 324 blocks
  hipLaunchKernelGGL(k1_prep, dim3(1), dim3(256), 0, stream, x, xmark, ymark, Wemb, bemb, ws);
  hipLaunchKernelGGL(k2_gi, dim3((G3*192 + PRED*G3 + 255)/256), dim3(256), 0, stream, Wih, bih, bhh, ws);
  hipLaunchKernelGGL(k3_enc, dim3(1), dim3(384), 0, stream, Whh, bhh, ws);
  hipLaunchKernelGGL(k4_dec, dim3(NSAMP/SPB), dim3(THR4), 0, stream, Whh, bhh, Wproj, bproj, ws, out);
}